// Round 6
// baseline (453.532 us; speedup 1.0000x reference)
//
#include <hip/hip_runtime.h>
#include <math.h>

namespace {
constexpr int COARSE = 32;
constexpr int NPT    = 767;   // N_INT - 1
constexpr int NRAYS  = 256;
constexpr double VOXEL_D = 1.3 * 2.0 / 32.0 / 4.0;
constexpr float  VOXEL_F = (float)VOXEL_D;
constexpr float  STEP_F  = (float)(VOXEL_D / 2.0);
constexpr float  RAD     = 1.3f;
}

// ---------------------------------------------------------------------------
// One block per ray (grid=256, 1024 threads, ~135 KiB LDS, 1 block/CU).
//  - atoms table (112 KiB) staged to LDS once per block
//  - each wave processes 2 sample points (32 lanes each, symmetric halves)
//  - coarse-cell loads are 32-lane contiguous float4 runs with wave dedup
//  - epilogue SH/sigma fold via a per-lane coefficient table built once
//  - transmittance scan fused (wave 0, from LDS) -> single kernel, no ws
// ---------------------------------------------------------------------------
__global__ __launch_bounds__(1024)
void shdict_render(const float* __restrict__ rays_o,
                   const float* __restrict__ rays_d,
                   const float* __restrict__ grid,
                   const float* __restrict__ atoms,
                   float* __restrict__ out)
{
  __shared__ float4 s_atoms[7168];      // full fine-atoms table, 112 KiB
  __shared__ float4 s_ktab[4][4][32];   // [ch][q][hl] fold table, 8 KiB
  __shared__ float  s_sh[9];
  __shared__ float  s_alpha[768];
  __shared__ float  s_rgb[768][3];

  const int ray  = blockIdx.x;
  const int tid  = threadIdx.x;
  const int lane = tid & 63;
  const int wv   = tid >> 6;           // wave 0..15
  const int half = (lane >> 5) & 1;    // which point of the pair
  const int hl   = lane & 31;          // lane within the half

  const float ox = rays_o[ray*3+0], oy = rays_o[ray*3+1], oz = rays_o[ray*3+2];
  const float dx = rays_d[ray*3+0], dy = rays_d[ray*3+1], dz = rays_d[ray*3+2];

  const float m0 = fminf((RAD - ox)/dx, (-RAD - ox)/dx);
  const float m1 = fminf((RAD - oy)/dy, (-RAD - oy)/dy);
  const float m2 = fminf((RAD - oz)/dz, (-RAD - oz)/dz);
  const float start = fmaxf(fmaxf(m0, m1), m2);
  const float dnorm = sqrtf(dx*dx + dy*dy + dz*dz);

  // --- stage atoms table (contiguous, 7 float4 per thread) ---
  const float4* at4 = (const float4*)atoms;
  #pragma unroll
  for (int k = 0; k < 7; ++k) {
    const int idx = tid + 1024*k;
    s_atoms[idx] = at4[idx];
  }
  if (tid == 0) {
    const float inx = dx/dnorm, iny = dy/dnorm, inz = dz/dnorm;
    s_sh[0] = 0.28209479177387814f;
    s_sh[1] = -0.4886025119029199f*iny;
    s_sh[2] =  0.4886025119029199f*inz;
    s_sh[3] = -0.4886025119029199f*inx;
    s_sh[4] =  1.0925484305920792f*inx*iny;
    s_sh[5] = -1.0925484305920792f*iny*inz;
    s_sh[6] =  0.31539156525252005f*(2.0f*inz*inz - inx*inx - iny*iny);
    s_sh[7] = -1.0925484305920792f*inx*inz;
    s_sh[8] =  0.5462742152960396f*(inx*inx - iny*iny);
  }
  __syncthreads();

  // --- build fold table: element e=4*(hl+32q)+comp -> (atom=e/28, d=e%28);
  //     channel 0..2 = rgb (coef sh[d%9]), channel 3 = sigma (d==27, coef 1) ---
  if (tid < 512) {
    const int hh = tid & 31;
    const int r  = tid >> 5;           // 0..15
    const int ch = r >> 2, q = r & 3;
    float vv[4];
    #pragma unroll
    for (int comp = 0; comp < 4; ++comp) {
      const int e = 4*(hh + 32*q) + comp;
      float val = 0.f;
      if (e < 448) {
        const int d = e % 28;
        if (d == 27) { if (ch == 3) val = 1.0f; }
        else if (d/9 == ch) val = s_sh[d % 9];
      }
      vv[comp] = val;
    }
    float4 v; v.x = vv[0]; v.y = vv[1]; v.z = vv[2]; v.w = vv[3];
    s_ktab[ch][q][hh] = v;
  }
  __syncthreads();

  const float4* gp4 = (const float4*)grid;

  // --- main gather loop: 24 iterations x 32 points (16 waves x 2) ---
  for (int it = 0; it < 24; ++it) {
    const int j = it*32 + wv*2 + half;
    const float t  = start + (float)j * STEP_F;
    const float px = ox + t*dx, py = oy + t*dy, pz = oz + t*dz;
    const bool inb = (px > -RAD) && (px < RAD) && (py > -RAD) && (py < RAD)
                  && (pz > -RAD) && (pz < RAD) && (j < NPT);
    float a = 0.f, r0 = 0.5f, r1 = 0.5f, r2 = 0.5f;

    if (__any(inb)) {
      const float ux = (px + RAD) / VOXEL_F;
      const float uy = (py + RAD) / VOXEL_F;
      const float uz = (pz + RAD) / VOXEL_F;

      float4 acc0 = make_float4(0.f,0.f,0.f,0.f);
      float4 acc1 = make_float4(0.f,0.f,0.f,0.f);
      float4 acc2 = make_float4(0.f,0.f,0.f,0.f);
      float4 acc3 = make_float4(0.f,0.f,0.f,0.f);
      float4 c0 = acc0, c1 = acc0, c2 = acc0, c3 = acc0;
      int pcell = -1;

      constexpr int gray[8] = {0,1,3,2,6,7,5,4};
      #pragma unroll
      for (int ci = 0; ci < 8; ++ci) {
        const int corner = gray[ci];
        const float sx = (corner & 4) ? 0.5f : -0.5f;
        const float sy = (corner & 2) ? 0.5f : -0.5f;
        const float sz = (corner & 1) ? 0.5f : -0.5f;
        const float pfx = fminf(fmaxf(floorf(ux + sx), 0.0f), 127.0f);
        const float pfy = fminf(fmaxf(floorf(uy + sy), 0.0f), 127.0f);
        const float pfz = fminf(fmaxf(floorf(uz + sz), 0.0f), 127.0f);
        const float fx = fabsf(ux - (pfx + 0.5f));
        const float fy = fabsf(uy - (pfy + 0.5f));
        const float fz = fabsf(uz - (pfz + 0.5f));
        const float w = (1.0f-fx)*(1.0f-fy)*(1.0f-fz);
        const int ix = (int)pfx, iy = (int)pfy, iz = (int)pfz;
        const int cell = ((ix >> 2)*COARSE + (iy >> 2))*COARSE + (iz >> 2);
        const int fine = ((ix & 3)*4 + (iy & 3))*4 + (iz & 3);

        if (__any(cell != pcell)) {        // reload-both (idempotent per lane)
          const float4* cv = gp4 + (size_t)cell*112 + hl;
          c0 = cv[0]; c1 = cv[32]; c2 = cv[64];
          if (hl < 16) c3 = cv[96];
        }
        pcell = cell;

        const float4* fp = s_atoms + fine*112 + hl;
        const float4 f0 = fp[0], f1 = fp[32], f2 = fp[64];
        acc0.x += w*c0.x*f0.x; acc0.y += w*c0.y*f0.y;
        acc0.z += w*c0.z*f0.z; acc0.w += w*c0.w*f0.w;
        acc1.x += w*c1.x*f1.x; acc1.y += w*c1.y*f1.y;
        acc1.z += w*c1.z*f1.z; acc1.w += w*c1.w*f1.w;
        acc2.x += w*c2.x*f2.x; acc2.y += w*c2.y*f2.y;
        acc2.z += w*c2.z*f2.z; acc2.w += w*c2.w*f2.w;
        if (hl < 16) {
          const float4 f3 = fp[96];
          acc3.x += w*c3.x*f3.x; acc3.y += w*c3.y*f3.y;
          acc3.z += w*c3.z*f3.z; acc3.w += w*c3.w*f3.w;
        }
      }

      // --- fold to (rgb_pre0..2, sigma) via table, then 5-round butterfly ---
      #define DOT4(K,V) ((K).x*(V).x + (K).y*(V).y + (K).z*(V).z + (K).w*(V).w)
      float b0 = DOT4(s_ktab[0][0][hl],acc0) + DOT4(s_ktab[0][1][hl],acc1)
               + DOT4(s_ktab[0][2][hl],acc2) + DOT4(s_ktab[0][3][hl],acc3);
      float b1 = DOT4(s_ktab[1][0][hl],acc0) + DOT4(s_ktab[1][1][hl],acc1)
               + DOT4(s_ktab[1][2][hl],acc2) + DOT4(s_ktab[1][3][hl],acc3);
      float b2 = DOT4(s_ktab[2][0][hl],acc0) + DOT4(s_ktab[2][1][hl],acc1)
               + DOT4(s_ktab[2][2][hl],acc2) + DOT4(s_ktab[2][3][hl],acc3);
      float b3 = DOT4(s_ktab[3][0][hl],acc0) + DOT4(s_ktab[3][1][hl],acc1)
               + DOT4(s_ktab[3][2][hl],acc2) + DOT4(s_ktab[3][3][hl],acc3);
      #undef DOT4
      #pragma unroll
      for (int off = 1; off < 32; off <<= 1) {
        b0 += __shfl_xor(b0, off, 64);
        b1 += __shfl_xor(b1, off, 64);
        b2 += __shfl_xor(b2, off, 64);
        b3 += __shfl_xor(b3, off, 64);
      }

      if (inb) {
        const float sigma = fmaxf(b3, 0.0f);
        a  = 1.0f - expf(-sigma * (STEP_F * dnorm));
        r0 = 1.0f/(1.0f + expf(-b0));
        r1 = 1.0f/(1.0f + expf(-b1));
        r2 = 1.0f/(1.0f + expf(-b2));
      }
    }

    if (hl == 0 && j < NPT) {
      s_alpha[j]  = a;
      s_rgb[j][0] = r0; s_rgb[j][1] = r1; s_rgb[j][2] = r2;
      out[NRAYS*3 + ray*NPT + j] = a;     // alpha output plane
    }
  }
  __syncthreads();

  // --- transmittance scan + reductions (wave 0) ---
  if (tid < 64) {
    const int ln = tid;
    float carry = 1.0f;
    float acc = 0.f, dep = 0.f, cc0 = 0.f, cc1 = 0.f, cc2 = 0.f;
    for (int chunk = 0; chunk < 12; ++chunk) {
      const int j = chunk*64 + ln;
      const float av = (j < NPT) ? s_alpha[j] : 0.0f;
      const float v = 1.0f - av + 1e-10f;
      float sp = v;
      #pragma unroll
      for (int off = 1; off < 64; off <<= 1) {
        const float o = __shfl_up(sp, off, 64);
        if (ln >= off) sp *= o;
      }
      float excl = __shfl_up(sp, 1, 64);
      if (ln == 0) excl = 1.0f;
      const float T = carry * excl;
      if (j < NPT) {
        const float al = av * T;
        acc += al;
        dep += al * (start + (float)j * STEP_F);
        cc0 += al * s_rgb[j][0];
        cc1 += al * s_rgb[j][1];
        cc2 += al * s_rgb[j][2];
      }
      carry *= __shfl(sp, 63, 64);
    }
    #pragma unroll
    for (int off = 32; off >= 1; off >>= 1) {
      acc += __shfl_down(acc, off, 64);
      dep += __shfl_down(dep, off, 64);
      cc0 += __shfl_down(cc0, off, 64);
      cc1 += __shfl_down(cc1, off, 64);
      cc2 += __shfl_down(cc2, off, 64);
    }
    if (ln == 0) {
      const float bg = 1.0f - acc;
      out[ray*3+0] = cc0 + bg;
      out[ray*3+1] = cc1 + bg;
      out[ray*3+2] = cc2 + bg;
      out[NRAYS*3 + NRAYS*NPT + ray] = dep;
      if (ray == 0) out[NRAYS*3 + NRAYS*NPT + NRAYS] = 0.0f;
    }
  }
}

extern "C" void kernel_launch(void* const* d_in, const int* in_sizes, int n_in,
                              void* d_out, int out_size, void* d_ws, size_t ws_size,
                              hipStream_t stream) {
  const float* rays_o = (const float*)d_in[0];
  const float* rays_d = (const float*)d_in[1];
  const float* grid   = (const float*)d_in[2];
  const float* atoms  = (const float*)d_in[3];
  (void)in_sizes; (void)n_in; (void)out_size; (void)d_ws; (void)ws_size;
  hipLaunchKernelGGL(shdict_render, dim3(NRAYS), dim3(1024), 0, stream,
                     rays_o, rays_d, grid, atoms, (float*)d_out);
}

// Round 8
// 245.313 us; speedup vs baseline: 1.8488x; 1.8488x over previous
//
#include <hip/hip_runtime.h>
#include <math.h>

namespace {
constexpr int COARSE = 32;
constexpr int NPT    = 767;   // N_INT - 1
constexpr int NRAYS  = 256;
constexpr int NPTS_TOTAL = NRAYS * NPT;          // 196352
constexpr int SEGS   = 48;                       // 48 segs * 16 pts = 768 >= 767
constexpr int GATHER_BLOCKS = NRAYS * SEGS;      // 12288 (% 8 == 0)
constexpr double VOXEL_D = 1.3 * 2.0 / 32.0 / 4.0;
constexpr float  VOXEL_F = (float)VOXEL_D;
constexpr float  STEP_F  = (float)(VOXEL_D / 2.0);
constexpr float  RAD     = 1.3f;
}

// ---------------------------------------------------------------------------
// Kernel A: 4 points per wave, 16 lanes per point. 256-thread block = 16
// consecutive sample points of one ray. Per-point setup/epilogue issue is
// amortized 4x vs R5 (95% VALU-issue-bound); the elementwise MAC stream is
// irreducible. Fold-table epilogue in 7 KiB LDS.
// R8 fix: table build is STRIDED over the 256-thread block (R7 used
// `if (tid < 448)` with only 256 threads -> entries 256..447 uninitialized).
// ---------------------------------------------------------------------------
__global__ __launch_bounds__(256)
void shdict_gather(const float* __restrict__ rays_o,
                   const float* __restrict__ rays_d,
                   const float* __restrict__ grid,
                   const float* __restrict__ atoms,
                   float* __restrict__ out,
                   float* __restrict__ ws)
{
  int bid = blockIdx.x;
  // XCD-chunked bijective swizzle (12288 % 8 == 0)
  bid = (bid & 7) * (GATHER_BLOCKS / 8) + (bid >> 3);

  const int ray  = bid / SEGS;
  const int seg  = bid - ray * SEGS;
  const int lane = threadIdx.x & 63;
  const int wv   = threadIdx.x >> 6;     // wave 0..3
  const int g    = lane >> 4;            // point group 0..3 within wave
  const int hl   = lane & 15;            // lane within point group
  const int j    = seg*16 + wv*4 + g;    // sample index (j==767 -> masked)

  __shared__ float4 s_ktab[448];         // [(ch*7+k)*16 + hl], 7 KiB

  const float ox = rays_o[ray*3+0], oy = rays_o[ray*3+1], oz = rays_o[ray*3+2];
  const float dx = rays_d[ray*3+0], dy = rays_d[ray*3+1], dz = rays_d[ray*3+2];

  const float m0 = fminf((RAD - ox)/dx, (-RAD - ox)/dx);
  const float m1 = fminf((RAD - oy)/dy, (-RAD - oy)/dy);
  const float m2 = fminf((RAD - oz)/dz, (-RAD - oz)/dz);
  const float start = fmaxf(fmaxf(m0, m1), m2);
  const float dnorm = sqrtf(dx*dx + dy*dy + dz*dz);
  const float inx = dx/dnorm, iny = dy/dnorm, inz = dz/dnorm;

  // --- build fold table once per block (strided: 448 entries, 256 threads) ---
  // element e = 4*(hh + 16*k) + comp -> (atom = e/28, d = e%28);
  // channels 0..2: rgb_pre (coef sh[d%9] when d/9==ch); channel 3: sigma (d==27)
  for (int tix = threadIdx.x; tix < 448; tix += 256) {
    const int ch  = tix / 112;
    const int rem = tix - ch*112;
    const int k   = rem >> 4;
    const int hh  = rem & 15;
    float vv[4];
    #pragma unroll
    for (int comp = 0; comp < 4; ++comp) {
      const int e = 4*(hh + 16*k) + comp;
      const int d = e % 28;
      const int dm = d % 9;
      const float shv =
        dm==0 ?  0.28209479177387814f :
        dm==1 ? -0.4886025119029199f*iny :
        dm==2 ?  0.4886025119029199f*inz :
        dm==3 ? -0.4886025119029199f*inx :
        dm==4 ?  1.0925484305920792f*inx*iny :
        dm==5 ? -1.0925484305920792f*iny*inz :
        dm==6 ?  0.31539156525252005f*(2.0f*inz*inz - inx*inx - iny*iny) :
        dm==7 ? -1.0925484305920792f*inx*inz :
                 0.5462742152960396f*(inx*inx - iny*iny);
      float val = 0.f;
      if (d == 27) { if (ch == 3) val = 1.0f; }
      else if (d/9 == ch) val = shv;
      vv[comp] = val;
    }
    float4 v; v.x = vv[0]; v.y = vv[1]; v.z = vv[2]; v.w = vv[3];
    s_ktab[(ch*7 + k)*16 + hh] = v;
  }
  __syncthreads();

  const float t  = start + (float)j * STEP_F;
  const float px = ox + t*dx, py = oy + t*dy, pz = oz + t*dz;
  const bool inb = (px > -RAD) && (px < RAD) && (py > -RAD) && (py < RAD)
                && (pz > -RAD) && (pz < RAD) && (j < NPT);

  float a = 0.f, r0 = 0.5f, r1 = 0.5f, r2 = 0.5f;

  if (__any(inb)) {
    const float ux = (px + RAD) / VOXEL_F;
    const float uy = (py + RAD) / VOXEL_F;
    const float uz = (pz + RAD) / VOXEL_F;

    const float4* gp4 = (const float4*)grid;
    const float4* ap4 = (const float4*)atoms;

    float4 c[7], acc[7];
    #pragma unroll
    for (int k = 0; k < 7; ++k) {
      c[k]   = make_float4(0.f,0.f,0.f,0.f);
      acc[k] = make_float4(0.f,0.f,0.f,0.f);
    }
    int pcell = -1;

    constexpr int gray[8] = {0,1,3,2,6,7,5,4};
    #pragma unroll
    for (int ci = 0; ci < 8; ++ci) {
      const int corner = gray[ci];
      const float sx = (corner & 4) ? 0.5f : -0.5f;
      const float sy = (corner & 2) ? 0.5f : -0.5f;
      const float sz = (corner & 1) ? 0.5f : -0.5f;
      const float pfx = fminf(fmaxf(floorf(ux + sx), 0.0f), 127.0f);
      const float pfy = fminf(fmaxf(floorf(uy + sy), 0.0f), 127.0f);
      const float pfz = fminf(fmaxf(floorf(uz + sz), 0.0f), 127.0f);
      const float fx = fabsf(ux - (pfx + 0.5f));
      const float fy = fabsf(uy - (pfy + 0.5f));
      const float fz = fabsf(uz - (pfz + 0.5f));
      const float w = (1.0f-fx)*(1.0f-fy)*(1.0f-fz);
      const int ix = (int)pfx, iy = (int)pfy, iz = (int)pfz;
      const int cell = ((ix >> 2)*COARSE + (iy >> 2))*COARSE + (iz >> 2);
      const int fine = ((ix & 3)*4 + (iy & 3))*4 + (iz & 3);

      if (__any(cell != pcell)) {            // wave-uniform reload (idempotent)
        const float4* cv = gp4 + (size_t)cell*112 + hl;
        #pragma unroll
        for (int k = 0; k < 7; ++k) c[k] = cv[16*k];
      }
      pcell = cell;

      const float4* fp = ap4 + (size_t)fine*112 + hl;
      #pragma unroll
      for (int k = 0; k < 7; ++k) {
        const float4 f = fp[16*k];
        acc[k].x += w * c[k].x * f.x;
        acc[k].y += w * c[k].y * f.y;
        acc[k].z += w * c[k].z * f.z;
        acc[k].w += w * c[k].w * f.w;
      }
    }

    // --- fold to (rgb_pre0..2, sigma) via LDS table, 4-round butterfly ---
    const float4* kt = s_ktab + hl;
    float b0 = 0.f, b1 = 0.f, b2 = 0.f, b3 = 0.f;
    #pragma unroll
    for (int k = 0; k < 7; ++k) {
      const float4 k0 = kt[(0*7 + k)*16];
      const float4 k1 = kt[(1*7 + k)*16];
      const float4 k2 = kt[(2*7 + k)*16];
      const float4 k3 = kt[(3*7 + k)*16];
      b0 += k0.x*acc[k].x + k0.y*acc[k].y + k0.z*acc[k].z + k0.w*acc[k].w;
      b1 += k1.x*acc[k].x + k1.y*acc[k].y + k1.z*acc[k].z + k1.w*acc[k].w;
      b2 += k2.x*acc[k].x + k2.y*acc[k].y + k2.z*acc[k].z + k2.w*acc[k].w;
      b3 += k3.x*acc[k].x + k3.y*acc[k].y + k3.z*acc[k].z + k3.w*acc[k].w;
    }
    #pragma unroll
    for (int off = 1; off < 16; off <<= 1) {
      b0 += __shfl_xor(b0, off, 64);
      b1 += __shfl_xor(b1, off, 64);
      b2 += __shfl_xor(b2, off, 64);
      b3 += __shfl_xor(b3, off, 64);
    }

    if (inb) {
      const float sigma = fmaxf(b3, 0.0f);
      a  = 1.0f - expf(-sigma * (STEP_F * dnorm));
      r0 = 1.0f/(1.0f + expf(-b0));
      r1 = 1.0f/(1.0f + expf(-b1));
      r2 = 1.0f/(1.0f + expf(-b2));
    }
  }

  if (hl == 0 && j < NPT) {
    const int p = ray*NPT + j;
    out[NRAYS*3 + p] = a;             // alpha output plane
    ws[0*NPTS_TOTAL + p] = r0;
    ws[1*NPTS_TOTAL + p] = r1;
    ws[2*NPTS_TOTAL + p] = r2;
  }
}

// ---------------------------------------------------------------------------
// Kernel B: transmittance scan + reductions. One wave per ray.
// ---------------------------------------------------------------------------
__global__ __launch_bounds__(256)
void shdict_scan(const float* __restrict__ rays_o,
                 const float* __restrict__ rays_d,
                 const float* __restrict__ ws,
                 float* __restrict__ out)
{
  const int wave = threadIdx.x >> 6;
  const int lane = threadIdx.x & 63;
  const int ray  = blockIdx.x * 4 + wave;
  if (ray >= NRAYS) return;

  const float ox = rays_o[ray*3+0], oy = rays_o[ray*3+1], oz = rays_o[ray*3+2];
  const float dx = rays_d[ray*3+0], dy = rays_d[ray*3+1], dz = rays_d[ray*3+2];
  const float m0 = fminf((RAD - ox)/dx, (-RAD - ox)/dx);
  const float m1 = fminf((RAD - oy)/dy, (-RAD - oy)/dy);
  const float m2 = fminf((RAD - oz)/dz, (-RAD - oz)/dz);
  const float start = fmaxf(fmaxf(m0, m1), m2);

  const float* alpha = out + NRAYS*3 + ray*NPT;

  float carry = 1.0f;
  float acc = 0.f, dep = 0.f, c0 = 0.f, c1 = 0.f, c2 = 0.f;
  for (int chunk = 0; chunk < 12; ++chunk) {
    const int j = chunk*64 + lane;
    const float a = (j < NPT) ? alpha[j] : 0.0f;
    const float v = 1.0f - a + 1e-10f;
    float s = v;
    #pragma unroll
    for (int off = 1; off < 64; off <<= 1) {
      const float o = __shfl_up(s, off, 64);
      if (lane >= off) s *= o;
    }
    float excl = __shfl_up(s, 1, 64);
    if (lane == 0) excl = 1.0f;
    const float T = carry * excl;
    if (j < NPT) {
      const int p = ray*NPT + j;
      const float al = a * T;
      acc += al;
      const float t = start + (float)j * STEP_F;
      dep += al * t;
      c0 += al * ws[0*NPTS_TOTAL + p];
      c1 += al * ws[1*NPTS_TOTAL + p];
      c2 += al * ws[2*NPTS_TOTAL + p];
    }
    carry *= __shfl(s, 63, 64);
  }
  #pragma unroll
  for (int off = 32; off >= 1; off >>= 1) {
    acc += __shfl_down(acc, off, 64);
    dep += __shfl_down(dep, off, 64);
    c0  += __shfl_down(c0,  off, 64);
    c1  += __shfl_down(c1,  off, 64);
    c2  += __shfl_down(c2,  off, 64);
  }
  if (lane == 0) {
    const float bg = 1.0f - acc;
    out[ray*3+0] = c0 + bg;
    out[ray*3+1] = c1 + bg;
    out[ray*3+2] = c2 + bg;
    out[NRAYS*3 + NRAYS*NPT + ray] = dep;
    if (ray == 0) out[NRAYS*3 + NRAYS*NPT + NRAYS] = 0.0f;
  }
}

// ---------------------------------------------------------------------------
// Fallback: fused single-kernel version (used only if ws is too small).
// ---------------------------------------------------------------------------
__global__ __launch_bounds__(256)
void shdict_render_fused(const float* __restrict__ rays_o,
                         const float* __restrict__ rays_d,
                         const float* __restrict__ grid,
                         const float* __restrict__ atoms,
                         float* __restrict__ out)
{
  const int ray = blockIdx.x;
  const int tid = threadIdx.x;

  __shared__ float s_alpha[NPT];
  __shared__ float s_rgb[NPT][3];

  const float ox = rays_o[ray*3+0], oy = rays_o[ray*3+1], oz = rays_o[ray*3+2];
  const float dx = rays_d[ray*3+0], dy = rays_d[ray*3+1], dz = rays_d[ray*3+2];

  const float m0 = fminf((RAD - ox)/dx, (-RAD - ox)/dx);
  const float m1 = fminf((RAD - oy)/dy, (-RAD - oy)/dy);
  const float m2 = fminf((RAD - oz)/dz, (-RAD - oz)/dz);
  const float start = fmaxf(fmaxf(m0, m1), m2);

  const float dnorm = sqrtf(dx*dx + dy*dy + dz*dz);
  const float inx = dx/dnorm, iny = dy/dnorm, inz = dz/dnorm;
  float sh[9];
  sh[0] = 0.28209479177387814f;
  sh[1] = -0.4886025119029199f*iny;
  sh[2] =  0.4886025119029199f*inz;
  sh[3] = -0.4886025119029199f*inx;
  sh[4] =  1.0925484305920792f*inx*iny;
  sh[5] = -1.0925484305920792f*iny*inz;
  sh[6] =  0.31539156525252005f*(2.0f*inz*inz - inx*inx - iny*iny);
  sh[7] = -1.0925484305920792f*inx*inz;
  sh[8] =  0.5462742152960396f*(inx*inx - iny*iny);

  float* alpha_out = out + NRAYS*3;

  for (int j = tid; j < NPT; j += 256) {
    const float t  = start + (float)j * STEP_F;
    const float px = ox + t*dx;
    const float py = oy + t*dy;
    const float pz = oz + t*dz;
    const bool inb = (px > -RAD) && (px < RAD) && (py > -RAD) && (py < RAD)
                  && (pz > -RAD) && (pz < RAD);
    float a = 0.0f, r0 = 0.5f, r1 = 0.5f, r2 = 0.5f;
    if (inb) {
      const float ux = (px + RAD) / VOXEL_F;
      const float uy = (py + RAD) / VOXEL_F;
      const float uz = (pz + RAD) / VOXEL_F;
      float4 acc4[7];
      #pragma unroll
      for (int q = 0; q < 7; ++q) acc4[q] = make_float4(0.f,0.f,0.f,0.f);
      for (int corner = 0; corner < 8; ++corner) {
        const float sx = (corner & 4) ? 0.5f : -0.5f;
        const float sy = (corner & 2) ? 0.5f : -0.5f;
        const float sz = (corner & 1) ? 0.5f : -0.5f;
        const float pfx = fminf(fmaxf(floorf(ux + sx), 0.0f), 127.0f);
        const float pfy = fminf(fmaxf(floorf(uy + sy), 0.0f), 127.0f);
        const float pfz = fminf(fmaxf(floorf(uz + sz), 0.0f), 127.0f);
        const float fx = fabsf(ux - (pfx + 0.5f));
        const float fy = fabsf(uy - (pfy + 0.5f));
        const float fz = fabsf(uz - (pfz + 0.5f));
        const float w = (1.0f-fx)*(1.0f-fy)*(1.0f-fz);
        const int ix = (int)pfx, iy = (int)pfy, iz = (int)pfz;
        const int cell = ((ix >> 2)*COARSE + (iy >> 2))*COARSE + (iz >> 2);
        const int fine = ((ix & 3)*4 + (iy & 3))*4 + (iz & 3);
        const float4* cv = (const float4*)(grid + (long)cell*448);
        const float4* fv = (const float4*)(atoms + (long)fine*448);
        float4 res[7];
        #pragma unroll
        for (int q = 0; q < 7; ++q) res[q] = make_float4(0.f,0.f,0.f,0.f);
        for (int aa = 0; aa < 16; ++aa) {
          #pragma unroll
          for (int q = 0; q < 7; ++q) {
            const float4 c = cv[aa*7 + q];
            const float4 f = fv[aa*7 + q];
            res[q].x += c.x*f.x;
            res[q].y += c.y*f.y;
            res[q].z += c.z*f.z;
            res[q].w += c.w*f.w;
          }
        }
        #pragma unroll
        for (int q = 0; q < 7; ++q) {
          acc4[q].x += w*res[q].x;
          acc4[q].y += w*res[q].y;
          acc4[q].z += w*res[q].z;
          acc4[q].w += w*res[q].w;
        }
      }
      const float* data = (const float*)acc4;
      const float sigma = fmaxf(data[27], 0.0f);
      a = 1.0f - expf(-sigma * (STEP_F * dnorm));
      float p0 = 0.f, p1 = 0.f, p2 = 0.f;
      #pragma unroll
      for (int k = 0; k < 9; ++k) {
        p0 += sh[k]*data[k];
        p1 += sh[k]*data[9+k];
        p2 += sh[k]*data[18+k];
      }
      r0 = 1.0f/(1.0f + expf(-p0));
      r1 = 1.0f/(1.0f + expf(-p1));
      r2 = 1.0f/(1.0f + expf(-p2));
    }
    s_alpha[j]  = a;
    s_rgb[j][0] = r0; s_rgb[j][1] = r1; s_rgb[j][2] = r2;
    alpha_out[ray*NPT + j] = a;
  }
  __syncthreads();

  if (tid < 64) {
    const int lane = tid;
    float carry = 1.0f;
    float acc = 0.f, dep = 0.f, c0 = 0.f, c1 = 0.f, c2 = 0.f;
    for (int chunk = 0; chunk < 12; ++chunk) {
      const int j = chunk*64 + lane;
      const float a = (j < NPT) ? s_alpha[j] : 0.0f;
      const float v = 1.0f - a + 1e-10f;
      float s = v;
      #pragma unroll
      for (int off = 1; off < 64; off <<= 1) {
        const float o = __shfl_up(s, off, 64);
        if (lane >= off) s *= o;
      }
      float excl = __shfl_up(s, 1, 64);
      if (lane == 0) excl = 1.0f;
      const float T = carry * excl;
      if (j < NPT) {
        const float al = a * T;
        acc += al;
        dep += al * (start + (float)j * STEP_F);
        c0 += al * s_rgb[j][0];
        c1 += al * s_rgb[j][1];
        c2 += al * s_rgb[j][2];
      }
      carry *= __shfl(s, 63, 64);
    }
    #pragma unroll
    for (int off = 32; off >= 1; off >>= 1) {
      acc += __shfl_down(acc, off, 64);
      dep += __shfl_down(dep, off, 64);
      c0  += __shfl_down(c0,  off, 64);
      c1  += __shfl_down(c1,  off, 64);
      c2  += __shfl_down(c2,  off, 64);
    }
    if (lane == 0) {
      const float bg = 1.0f - acc;
      out[ray*3+0] = c0 + bg;
      out[ray*3+1] = c1 + bg;
      out[ray*3+2] = c2 + bg;
      out[NRAYS*3 + NRAYS*NPT + ray] = dep;
      if (ray == 0) out[NRAYS*3 + NRAYS*NPT + NRAYS] = 0.0f;
    }
  }
}

extern "C" void kernel_launch(void* const* d_in, const int* in_sizes, int n_in,
                              void* d_out, int out_size, void* d_ws, size_t ws_size,
                              hipStream_t stream) {
  const float* rays_o = (const float*)d_in[0];
  const float* rays_d = (const float*)d_in[1];
  const float* grid   = (const float*)d_in[2];
  const float* atoms  = (const float*)d_in[3];
  (void)in_sizes; (void)n_in; (void)out_size;

  const size_t ws_needed = (size_t)3 * NPTS_TOTAL * sizeof(float);
  if (ws_size >= ws_needed) {
    hipLaunchKernelGGL(shdict_gather, dim3(GATHER_BLOCKS), dim3(256), 0, stream,
                       rays_o, rays_d, grid, atoms, (float*)d_out, (float*)d_ws);
    hipLaunchKernelGGL(shdict_scan, dim3(NRAYS/4), dim3(256), 0, stream,
                       rays_o, rays_d, (const float*)d_ws, (float*)d_out);
  } else {
    hipLaunchKernelGGL(shdict_render_fused, dim3(NRAYS), dim3(256), 0, stream,
                       rays_o, rays_d, grid, atoms, (float*)d_out);
  }
}

// Round 9
// 240.130 us; speedup vs baseline: 1.8887x; 1.0216x over previous
//
#include <hip/hip_runtime.h>
#include <math.h>

namespace {
constexpr int COARSE = 32;
constexpr int NPT    = 767;   // N_INT - 1
constexpr int NRAYS  = 256;
constexpr int NPTS_TOTAL = NRAYS * NPT;          // 196352
constexpr int SEGS   = 96;                       // 96 segs * 8 pts = 768 >= 767
constexpr int GATHER_BLOCKS = NRAYS * SEGS;      // 24576 (% 8 == 0)
constexpr double VOXEL_D = 1.3 * 2.0 / 32.0 / 4.0;
constexpr float  VOXEL_F = (float)VOXEL_D;
constexpr float  STEP_F  = (float)(VOXEL_D / 2.0);
constexpr float  RAD     = 1.3f;
}

// ---------------------------------------------------------------------------
// Kernel A: 2 points per wave, 32 lanes per point (the R5<->R8 sweet spot:
// R5 = 1pt/wave: 48 VGPR, 50% occ, 95% VALU-issue-bound, 137us;
// R8 = 4pt/wave: 224 VGPR, 11% occ, latency-bound, 245us).
// Per-lane data state is 14 acc + 14 cached-cv regs -> target VGPR <= 128.
// Corner geometry / preamble / epilogue issue once per 2 points.
// Fold-table epilogue in 8 KiB LDS (512 float4, built strided by 256 thr).
// ---------------------------------------------------------------------------
__global__ __launch_bounds__(256)
void shdict_gather(const float* __restrict__ rays_o,
                   const float* __restrict__ rays_d,
                   const float* __restrict__ grid,
                   const float* __restrict__ atoms,
                   float* __restrict__ out,
                   float* __restrict__ ws)
{
  int bid = blockIdx.x;
  // XCD-chunked bijective swizzle (24576 % 8 == 0)
  bid = (bid & 7) * (GATHER_BLOCKS / 8) + (bid >> 3);

  const int ray  = bid / SEGS;
  const int seg  = bid - ray * SEGS;
  const int lane = threadIdx.x & 63;
  const int wv   = threadIdx.x >> 6;     // wave 0..3
  const int half = lane >> 5;            // which point of the pair
  const int hl   = lane & 31;            // lane within the point
  const int j    = seg*8 + wv*2 + half;  // sample index (j==767 -> masked)

  __shared__ float4 s_ktab[512];         // [(ch*4+q)*32 + hl], 8 KiB

  const float ox = rays_o[ray*3+0], oy = rays_o[ray*3+1], oz = rays_o[ray*3+2];
  const float dx = rays_d[ray*3+0], dy = rays_d[ray*3+1], dz = rays_d[ray*3+2];

  const float m0 = fminf((RAD - ox)/dx, (-RAD - ox)/dx);
  const float m1 = fminf((RAD - oy)/dy, (-RAD - oy)/dy);
  const float m2 = fminf((RAD - oz)/dz, (-RAD - oz)/dz);
  const float start = fmaxf(fmaxf(m0, m1), m2);
  const float dnorm = sqrtf(dx*dx + dy*dy + dz*dz);
  const float inx = dx/dnorm, iny = dy/dnorm, inz = dz/dnorm;

  // --- build fold table (512 float4 entries, strided over 256 threads) ---
  // entry tix = ch*128 + q*32 + hh; component comp holds coef for element
  // e = 4*(hh + 32*q) + comp of a point's 448-float cell contraction:
  //   d = e%28; ch 0..2 -> rgb_pre coef sh[d%9] iff d/9==ch; ch 3 -> d==27.
  for (int tix = threadIdx.x; tix < 512; tix += 256) {
    const int q  = (tix >> 5) & 3;
    const int ch = tix >> 7;
    const int hh = tix & 31;
    float vv[4];
    #pragma unroll
    for (int comp = 0; comp < 4; ++comp) {
      const int e = 4*(hh + 32*q) + comp;
      float val = 0.f;
      if (e < 448) {
        const int d = e % 28;
        const int dm = d % 9;
        const float shv =
          dm==0 ?  0.28209479177387814f :
          dm==1 ? -0.4886025119029199f*iny :
          dm==2 ?  0.4886025119029199f*inz :
          dm==3 ? -0.4886025119029199f*inx :
          dm==4 ?  1.0925484305920792f*inx*iny :
          dm==5 ? -1.0925484305920792f*iny*inz :
          dm==6 ?  0.31539156525252005f*(2.0f*inz*inz - inx*inx - iny*iny) :
          dm==7 ? -1.0925484305920792f*inx*inz :
                   0.5462742152960396f*(inx*inx - iny*iny);
        if (d == 27) { if (ch == 3) val = 1.0f; }
        else if (d/9 == ch) val = shv;
      }
      vv[comp] = val;
    }
    float4 v; v.x = vv[0]; v.y = vv[1]; v.z = vv[2]; v.w = vv[3];
    s_ktab[tix] = v;
  }
  __syncthreads();

  const float t  = start + (float)j * STEP_F;
  const float px = ox + t*dx, py = oy + t*dy, pz = oz + t*dz;
  const bool inb = (px > -RAD) && (px < RAD) && (py > -RAD) && (py < RAD)
                && (pz > -RAD) && (pz < RAD) && (j < NPT);

  float a = 0.f, r0 = 0.5f, r1 = 0.5f, r2 = 0.5f;

  if (__any(inb)) {
    const float ux = (px + RAD) / VOXEL_F;
    const float uy = (py + RAD) / VOXEL_F;
    const float uz = (pz + RAD) / VOXEL_F;

    const float4* gp4 = (const float4*)grid;
    const float4* ap4 = (const float4*)atoms;

    float4 c0 = make_float4(0.f,0.f,0.f,0.f), c1 = c0, c2 = c0, c3 = c0;
    float4 a0 = c0, a1 = c0, a2 = c0, a3 = c0;
    int pcell = -1;

    constexpr int gray[8] = {0,1,3,2,6,7,5,4};
    #pragma unroll
    for (int ci = 0; ci < 8; ++ci) {
      const int corner = gray[ci];
      const float sx = (corner & 4) ? 0.5f : -0.5f;
      const float sy = (corner & 2) ? 0.5f : -0.5f;
      const float sz = (corner & 1) ? 0.5f : -0.5f;
      const float pfx = fminf(fmaxf(floorf(ux + sx), 0.0f), 127.0f);
      const float pfy = fminf(fmaxf(floorf(uy + sy), 0.0f), 127.0f);
      const float pfz = fminf(fmaxf(floorf(uz + sz), 0.0f), 127.0f);
      const float fx = fabsf(ux - (pfx + 0.5f));
      const float fy = fabsf(uy - (pfy + 0.5f));
      const float fz = fabsf(uz - (pfz + 0.5f));
      const float w = (1.0f-fx)*(1.0f-fy)*(1.0f-fz);
      const int ix = (int)pfx, iy = (int)pfy, iz = (int)pfz;
      const int cell = ((ix >> 2)*COARSE + (iy >> 2))*COARSE + (iz >> 2);
      const int fine = ((ix & 3)*4 + (iy & 3))*4 + (iz & 3);

      if (__any(cell != pcell)) {            // wave-uniform reload (idempotent)
        const float4* cv = gp4 + (size_t)cell*112;
        c0 = cv[hl]; c1 = cv[32+hl]; c2 = cv[64+hl];
        if (hl < 16) c3 = cv[96+hl];
      }
      pcell = cell;

      const float4* fp = ap4 + (size_t)fine*112;
      const float4 f0 = fp[hl], f1 = fp[32+hl], f2 = fp[64+hl];
      a0.x += w*c0.x*f0.x; a0.y += w*c0.y*f0.y;
      a0.z += w*c0.z*f0.z; a0.w += w*c0.w*f0.w;
      a1.x += w*c1.x*f1.x; a1.y += w*c1.y*f1.y;
      a1.z += w*c1.z*f1.z; a1.w += w*c1.w*f1.w;
      a2.x += w*c2.x*f2.x; a2.y += w*c2.y*f2.y;
      a2.z += w*c2.z*f2.z; a2.w += w*c2.w*f2.w;
      if (hl < 16) {
        const float4 f3 = fp[96+hl];
        a3.x += w*c3.x*f3.x; a3.y += w*c3.y*f3.y;
        a3.z += w*c3.z*f3.z; a3.w += w*c3.w*f3.w;
      }
    }

    // --- fold to (rgb_pre0..2, sigma) via LDS table, 5-round butterfly ---
    const float4* kt = s_ktab + hl;
    #define DOT4(K,V) ((K).x*(V).x + (K).y*(V).y + (K).z*(V).z + (K).w*(V).w)
    float b0 = DOT4(kt[  0],a0) + DOT4(kt[ 32],a1) + DOT4(kt[ 64],a2) + DOT4(kt[ 96],a3);
    float b1 = DOT4(kt[128],a0) + DOT4(kt[160],a1) + DOT4(kt[192],a2) + DOT4(kt[224],a3);
    float b2 = DOT4(kt[256],a0) + DOT4(kt[288],a1) + DOT4(kt[320],a2) + DOT4(kt[352],a3);
    float b3 = DOT4(kt[384],a0) + DOT4(kt[416],a1) + DOT4(kt[448],a2) + DOT4(kt[480],a3);
    #undef DOT4
    #pragma unroll
    for (int off = 1; off < 32; off <<= 1) {
      b0 += __shfl_xor(b0, off, 64);
      b1 += __shfl_xor(b1, off, 64);
      b2 += __shfl_xor(b2, off, 64);
      b3 += __shfl_xor(b3, off, 64);
    }

    if (inb) {
      const float sigma = fmaxf(b3, 0.0f);
      a  = 1.0f - expf(-sigma * (STEP_F * dnorm));
      r0 = 1.0f/(1.0f + expf(-b0));
      r1 = 1.0f/(1.0f + expf(-b1));
      r2 = 1.0f/(1.0f + expf(-b2));
    }
  }

  if (hl == 0 && j < NPT) {
    const int p = ray*NPT + j;
    out[NRAYS*3 + p] = a;             // alpha output plane
    ws[0*NPTS_TOTAL + p] = r0;
    ws[1*NPTS_TOTAL + p] = r1;
    ws[2*NPTS_TOTAL + p] = r2;
  }
}

// ---------------------------------------------------------------------------
// Kernel B: transmittance scan + reductions. One wave per ray.
// ---------------------------------------------------------------------------
__global__ __launch_bounds__(256)
void shdict_scan(const float* __restrict__ rays_o,
                 const float* __restrict__ rays_d,
                 const float* __restrict__ ws,
                 float* __restrict__ out)
{
  const int wave = threadIdx.x >> 6;
  const int lane = threadIdx.x & 63;
  const int ray  = blockIdx.x * 4 + wave;
  if (ray >= NRAYS) return;

  const float ox = rays_o[ray*3+0], oy = rays_o[ray*3+1], oz = rays_o[ray*3+2];
  const float dx = rays_d[ray*3+0], dy = rays_d[ray*3+1], dz = rays_d[ray*3+2];
  const float m0 = fminf((RAD - ox)/dx, (-RAD - ox)/dx);
  const float m1 = fminf((RAD - oy)/dy, (-RAD - oy)/dy);
  const float m2 = fminf((RAD - oz)/dz, (-RAD - oz)/dz);
  const float start = fmaxf(fmaxf(m0, m1), m2);

  const float* alpha = out + NRAYS*3 + ray*NPT;

  float carry = 1.0f;
  float acc = 0.f, dep = 0.f, c0 = 0.f, c1 = 0.f, c2 = 0.f;
  for (int chunk = 0; chunk < 12; ++chunk) {
    const int j = chunk*64 + lane;
    const float a = (j < NPT) ? alpha[j] : 0.0f;
    const float v = 1.0f - a + 1e-10f;
    float s = v;
    #pragma unroll
    for (int off = 1; off < 64; off <<= 1) {
      const float o = __shfl_up(s, off, 64);
      if (lane >= off) s *= o;
    }
    float excl = __shfl_up(s, 1, 64);
    if (lane == 0) excl = 1.0f;
    const float T = carry * excl;
    if (j < NPT) {
      const int p = ray*NPT + j;
      const float al = a * T;
      acc += al;
      const float t = start + (float)j * STEP_F;
      dep += al * t;
      c0 += al * ws[0*NPTS_TOTAL + p];
      c1 += al * ws[1*NPTS_TOTAL + p];
      c2 += al * ws[2*NPTS_TOTAL + p];
    }
    carry *= __shfl(s, 63, 64);
  }
  #pragma unroll
  for (int off = 32; off >= 1; off >>= 1) {
    acc += __shfl_down(acc, off, 64);
    dep += __shfl_down(dep, off, 64);
    c0  += __shfl_down(c0,  off, 64);
    c1  += __shfl_down(c1,  off, 64);
    c2  += __shfl_down(c2,  off, 64);
  }
  if (lane == 0) {
    const float bg = 1.0f - acc;
    out[ray*3+0] = c0 + bg;
    out[ray*3+1] = c1 + bg;
    out[ray*3+2] = c2 + bg;
    out[NRAYS*3 + NRAYS*NPT + ray] = dep;
    if (ray == 0) out[NRAYS*3 + NRAYS*NPT + NRAYS] = 0.0f;
  }
}

// ---------------------------------------------------------------------------
// Fallback: fused single-kernel version (used only if ws is too small).
// ---------------------------------------------------------------------------
__global__ __launch_bounds__(256)
void shdict_render_fused(const float* __restrict__ rays_o,
                         const float* __restrict__ rays_d,
                         const float* __restrict__ grid,
                         const float* __restrict__ atoms,
                         float* __restrict__ out)
{
  const int ray = blockIdx.x;
  const int tid = threadIdx.x;

  __shared__ float s_alpha[NPT];
  __shared__ float s_rgb[NPT][3];

  const float ox = rays_o[ray*3+0], oy = rays_o[ray*3+1], oz = rays_o[ray*3+2];
  const float dx = rays_d[ray*3+0], dy = rays_d[ray*3+1], dz = rays_d[ray*3+2];

  const float m0 = fminf((RAD - ox)/dx, (-RAD - ox)/dx);
  const float m1 = fminf((RAD - oy)/dy, (-RAD - oy)/dy);
  const float m2 = fminf((RAD - oz)/dz, (-RAD - oz)/dz);
  const float start = fmaxf(fmaxf(m0, m1), m2);

  const float dnorm = sqrtf(dx*dx + dy*dy + dz*dz);
  const float inx = dx/dnorm, iny = dy/dnorm, inz = dz/dnorm;
  float sh[9];
  sh[0] = 0.28209479177387814f;
  sh[1] = -0.4886025119029199f*iny;
  sh[2] =  0.4886025119029199f*inz;
  sh[3] = -0.4886025119029199f*inx;
  sh[4] =  1.0925484305920792f*inx*iny;
  sh[5] = -1.0925484305920792f*iny*inz;
  sh[6] =  0.31539156525252005f*(2.0f*inz*inz - inx*inx - iny*iny);
  sh[7] = -1.0925484305920792f*inx*inz;
  sh[8] =  0.5462742152960396f*(inx*inx - iny*iny);

  float* alpha_out = out + NRAYS*3;

  for (int j = tid; j < NPT; j += 256) {
    const float t  = start + (float)j * STEP_F;
    const float px = ox + t*dx;
    const float py = oy + t*dy;
    const float pz = oz + t*dz;
    const bool inb = (px > -RAD) && (px < RAD) && (py > -RAD) && (py < RAD)
                  && (pz > -RAD) && (pz < RAD);
    float a = 0.0f, r0 = 0.5f, r1 = 0.5f, r2 = 0.5f;
    if (inb) {
      const float ux = (px + RAD) / VOXEL_F;
      const float uy = (py + RAD) / VOXEL_F;
      const float uz = (pz + RAD) / VOXEL_F;
      float4 acc4[7];
      #pragma unroll
      for (int q = 0; q < 7; ++q) acc4[q] = make_float4(0.f,0.f,0.f,0.f);
      for (int corner = 0; corner < 8; ++corner) {
        const float sx = (corner & 4) ? 0.5f : -0.5f;
        const float sy = (corner & 2) ? 0.5f : -0.5f;
        const float sz = (corner & 1) ? 0.5f : -0.5f;
        const float pfx = fminf(fmaxf(floorf(ux + sx), 0.0f), 127.0f);
        const float pfy = fminf(fmaxf(floorf(uy + sy), 0.0f), 127.0f);
        const float pfz = fminf(fmaxf(floorf(uz + sz), 0.0f), 127.0f);
        const float fx = fabsf(ux - (pfx + 0.5f));
        const float fy = fabsf(uy - (pfy + 0.5f));
        const float fz = fabsf(uz - (pfz + 0.5f));
        const float w = (1.0f-fx)*(1.0f-fy)*(1.0f-fz);
        const int ix = (int)pfx, iy = (int)pfy, iz = (int)pfz;
        const int cell = ((ix >> 2)*COARSE + (iy >> 2))*COARSE + (iz >> 2);
        const int fine = ((ix & 3)*4 + (iy & 3))*4 + (iz & 3);
        const float4* cv = (const float4*)(grid + (long)cell*448);
        const float4* fv = (const float4*)(atoms + (long)fine*448);
        float4 res[7];
        #pragma unroll
        for (int q = 0; q < 7; ++q) res[q] = make_float4(0.f,0.f,0.f,0.f);
        for (int aa = 0; aa < 16; ++aa) {
          #pragma unroll
          for (int q = 0; q < 7; ++q) {
            const float4 c = cv[aa*7 + q];
            const float4 f = fv[aa*7 + q];
            res[q].x += c.x*f.x;
            res[q].y += c.y*f.y;
            res[q].z += c.z*f.z;
            res[q].w += c.w*f.w;
          }
        }
        #pragma unroll
        for (int q = 0; q < 7; ++q) {
          acc4[q].x += w*res[q].x;
          acc4[q].y += w*res[q].y;
          acc4[q].z += w*res[q].z;
          acc4[q].w += w*res[q].w;
        }
      }
      const float* data = (const float*)acc4;
      const float sigma = fmaxf(data[27], 0.0f);
      a = 1.0f - expf(-sigma * (STEP_F * dnorm));
      float p0 = 0.f, p1 = 0.f, p2 = 0.f;
      #pragma unroll
      for (int k = 0; k < 9; ++k) {
        p0 += sh[k]*data[k];
        p1 += sh[k]*data[9+k];
        p2 += sh[k]*data[18+k];
      }
      r0 = 1.0f/(1.0f + expf(-p0));
      r1 = 1.0f/(1.0f + expf(-p1));
      r2 = 1.0f/(1.0f + expf(-p2));
    }
    s_alpha[j]  = a;
    s_rgb[j][0] = r0; s_rgb[j][1] = r1; s_rgb[j][2] = r2;
    alpha_out[ray*NPT + j] = a;
  }
  __syncthreads();

  if (tid < 64) {
    const int lane = tid;
    float carry = 1.0f;
    float acc = 0.f, dep = 0.f, c0 = 0.f, c1 = 0.f, c2 = 0.f;
    for (int chunk = 0; chunk < 12; ++chunk) {
      const int j = chunk*64 + lane;
      const float a = (j < NPT) ? s_alpha[j] : 0.0f;
      const float v = 1.0f - a + 1e-10f;
      float s = v;
      #pragma unroll
      for (int off = 1; off < 64; off <<= 1) {
        const float o = __shfl_up(s, off, 64);
        if (lane >= off) s *= o;
      }
      float excl = __shfl_up(s, 1, 64);
      if (lane == 0) excl = 1.0f;
      const float T = carry * excl;
      if (j < NPT) {
        const float al = a * T;
        acc += al;
        dep += al * (start + (float)j * STEP_F);
        c0 += al * s_rgb[j][0];
        c1 += al * s_rgb[j][1];
        c2 += al * s_rgb[j][2];
      }
      carry *= __shfl(s, 63, 64);
    }
    #pragma unroll
    for (int off = 32; off >= 1; off >>= 1) {
      acc += __shfl_down(acc, off, 64);
      dep += __shfl_down(dep, off, 64);
      c0  += __shfl_down(c0,  off, 64);
      c1  += __shfl_down(c1,  off, 64);
      c2  += __shfl_down(c2,  off, 64);
    }
    if (lane == 0) {
      const float bg = 1.0f - acc;
      out[ray*3+0] = c0 + bg;
      out[ray*3+1] = c1 + bg;
      out[ray*3+2] = c2 + bg;
      out[NRAYS*3 + NRAYS*NPT + ray] = dep;
      if (ray == 0) out[NRAYS*3 + NRAYS*NPT + NRAYS] = 0.0f;
    }
  }
}

extern "C" void kernel_launch(void* const* d_in, const int* in_sizes, int n_in,
                              void* d_out, int out_size, void* d_ws, size_t ws_size,
                              hipStream_t stream) {
  const float* rays_o = (const float*)d_in[0];
  const float* rays_d = (const float*)d_in[1];
  const float* grid   = (const float*)d_in[2];
  const float* atoms  = (const float*)d_in[3];
  (void)in_sizes; (void)n_in; (void)out_size;

  const size_t ws_needed = (size_t)3 * NPTS_TOTAL * sizeof(float);
  if (ws_size >= ws_needed) {
    hipLaunchKernelGGL(shdict_gather, dim3(GATHER_BLOCKS), dim3(256), 0, stream,
                       rays_o, rays_d, grid, atoms, (float*)d_out, (float*)d_ws);
    hipLaunchKernelGGL(shdict_scan, dim3(NRAYS/4), dim3(256), 0, stream,
                       rays_o, rays_d, (const float*)d_ws, (float*)d_out);
  } else {
    hipLaunchKernelGGL(shdict_render_fused, dim3(NRAYS), dim3(256), 0, stream,
                       rays_o, rays_d, grid, atoms, (float*)d_out);
  }
}

// Round 10
// 107.188 us; speedup vs baseline: 4.2312x; 2.2403x over previous
//
#include <hip/hip_runtime.h>
#include <math.h>

namespace {
constexpr int COARSE = 32;
constexpr int NPT    = 767;   // N_INT - 1
constexpr int NRAYS  = 256;
constexpr int NPTS_TOTAL = NRAYS * NPT;        // 196352
// Max in-cube samples per ray: chord <= 2*R*sqrt(3) = 4.503; STEP = 0.0203125
// -> j < 221.7. JMAX = 224 (margin ~2.3 steps >> fp32 rounding).
constexpr int JMAX   = 224;
constexpr int PTS_PER_BLK = 4;                 // 4 waves, 1 point per wave
constexpr int SEGS   = JMAX / PTS_PER_BLK;     // 56
constexpr int GATHER_BLOCKS = NRAYS * SEGS;    // 14336 (% 8 == 0)
constexpr int WS_RAY_STRIDE = 256;             // compacted rgb ws: j < 256
constexpr int WS_PLANE = NRAYS * WS_RAY_STRIDE; // 65536
constexpr double VOXEL_D = 1.3 * 2.0 / 32.0 / 4.0;
constexpr float  VOXEL_F = (float)VOXEL_D;
constexpr float  STEP_F  = (float)(VOXEL_D / 2.0);
constexpr float  RAD     = 1.3f;
}

// ---------------------------------------------------------------------------
// Kernel A: one 64-lane wave per sample point (R5 champion structure), but
// only j < 224 (all j >= 224 are provably out-of-cube; alpha there = 0 via
// memsetAsync). Slim corner body: per-axis lo/hi voxel data precomputed once
// per point (weights + premultiplied float4 offsets); per corner only
// 2 muls + 4 adds + loads + MACs. Fold-table epilogue (8 KiB LDS, strided
// build). Conservative whole-block early-out via closed-form exit distance.
// ---------------------------------------------------------------------------
__global__ __launch_bounds__(256)
void shdict_gather(const float* __restrict__ rays_o,
                   const float* __restrict__ rays_d,
                   const float* __restrict__ grid,
                   const float* __restrict__ atoms,
                   float* __restrict__ out,
                   float* __restrict__ ws)
{
  int bid = blockIdx.x;
  // XCD-chunked bijective swizzle (14336 % 8 == 0)
  bid = (bid & 7) * (GATHER_BLOCKS / 8) + (bid >> 3);

  const int ray  = bid / SEGS;
  const int seg  = bid - ray * SEGS;
  const int lane = threadIdx.x & 63;
  const int wv   = threadIdx.x >> 6;     // wave 0..3
  const int j    = seg * 4 + wv;         // sample index, < 224

  __shared__ float4 s_ktab[512];         // [ch*128 + f4idx], 8 KiB (padded)

  const float ox = rays_o[ray*3+0], oy = rays_o[ray*3+1], oz = rays_o[ray*3+2];
  const float dx = rays_d[ray*3+0], dy = rays_d[ray*3+1], dz = rays_d[ray*3+2];

  const float ax0 = (RAD - ox)/dx, ax1 = (-RAD - ox)/dx;
  const float ay0 = (RAD - oy)/dy, ay1 = (-RAD - oy)/dy;
  const float az0 = (RAD - oz)/dz, az1 = (-RAD - oz)/dz;
  const float start = fmaxf(fmaxf(fminf(ax0,ax1), fminf(ay0,ay1)), fminf(az0,az1));
  const float texit = fminf(fminf(fmaxf(ax0,ax1), fmaxf(ay0,ay1)), fmaxf(az0,az1));

  // Whole-block early-out (block-uniform; conservative margin of 2 steps).
  // NaN-safe: comparison false -> falls through to exact per-point inb.
  const float jexit = (texit - start) / STEP_F;
  if ((float)(seg*4) > jexit + 2.0f) return;

  const float dnorm = sqrtf(dx*dx + dy*dy + dz*dz);
  const float inx = dx/dnorm, iny = dy/dnorm, inz = dz/dnorm;

  // --- fold table: 512 float4 entries, STRIDED build over 256 threads ---
  // entry [ch*128 + fi] covers elements e = 4*fi..4*fi+3 (fi < 112; else 0):
  //   d = e%28; ch 0..2 -> sh[d%9] iff d/9==ch; ch 3 -> (d==27).
  for (int tix = threadIdx.x; tix < 512; tix += 256) {
    const int ch = tix >> 7;
    const int fi = tix & 127;
    float vv[4];
    #pragma unroll
    for (int comp = 0; comp < 4; ++comp) {
      float val = 0.f;
      if (fi < 112) {
        const int e = 4*fi + comp;
        const int d = e % 28;
        const int dm = d % 9;
        const float shv =
          dm==0 ?  0.28209479177387814f :
          dm==1 ? -0.4886025119029199f*iny :
          dm==2 ?  0.4886025119029199f*inz :
          dm==3 ? -0.4886025119029199f*inx :
          dm==4 ?  1.0925484305920792f*inx*iny :
          dm==5 ? -1.0925484305920792f*iny*inz :
          dm==6 ?  0.31539156525252005f*(2.0f*inz*inz - inx*inx - iny*iny) :
          dm==7 ? -1.0925484305920792f*inx*inz :
                   0.5462742152960396f*(inx*inx - iny*iny);
        if (d == 27) { if (ch == 3) val = 1.0f; }
        else if (d/9 == ch) val = shv;
      }
      vv[comp] = val;
    }
    float4 v; v.x = vv[0]; v.y = vv[1]; v.z = vv[2]; v.w = vv[3];
    s_ktab[tix] = v;
  }
  __syncthreads();

  const float t  = start + (float)j * STEP_F;
  const float px = ox + t*dx, py = oy + t*dy, pz = oz + t*dz;
  const bool inb = (px > -RAD) && (px < RAD) && (py > -RAD) && (py < RAD)
                && (pz > -RAD) && (pz < RAD);   // wave-uniform (1 pt/wave)

  float a = 0.f, r0 = 0.5f, r1 = 0.5f, r2 = 0.5f;

  if (inb) {
    const float ux = (px + RAD) / VOXEL_F;
    const float uy = (py + RAD) / VOXEL_F;
    const float uz = (pz + RAD) / VOXEL_F;

    // --- per-axis lo/hi voxel data (once per point) ---
    const float pfx0 = fminf(fmaxf(floorf(ux - 0.5f), 0.0f), 127.0f);
    const float pfx1 = fminf(fmaxf(floorf(ux + 0.5f), 0.0f), 127.0f);
    const float pfy0 = fminf(fmaxf(floorf(uy - 0.5f), 0.0f), 127.0f);
    const float pfy1 = fminf(fmaxf(floorf(uy + 0.5f), 0.0f), 127.0f);
    const float pfz0 = fminf(fmaxf(floorf(uz - 0.5f), 0.0f), 127.0f);
    const float pfz1 = fminf(fmaxf(floorf(uz + 0.5f), 0.0f), 127.0f);
    const float wx0 = 1.0f - fabsf(ux - (pfx0 + 0.5f));
    const float wx1 = 1.0f - fabsf(ux - (pfx1 + 0.5f));
    const float wy0 = 1.0f - fabsf(uy - (pfy0 + 0.5f));
    const float wy1 = 1.0f - fabsf(uy - (pfy1 + 0.5f));
    const float wz0 = 1.0f - fabsf(uz - (pfz0 + 0.5f));
    const float wz1 = 1.0f - fabsf(uz - (pfz1 + 0.5f));
    const int ix0 = (int)pfx0, ix1 = (int)pfx1;
    const int iy0 = (int)pfy0, iy1 = (int)pfy1;
    const int iz0 = (int)pfz0, iz1 = (int)pfz1;
    // premultiplied float4-offsets: cell*112 and fine*112 decomposed per axis
    const int cpx0 = (ix0 >> 2) * 114688, cpx1 = (ix1 >> 2) * 114688;
    const int cpy0 = (iy0 >> 2) * 3584,   cpy1 = (iy1 >> 2) * 3584;
    const int cpz0 = (iz0 >> 2) * 112,    cpz1 = (iz1 >> 2) * 112;
    const int fpx0 = (ix0 & 3) * 1792,    fpx1 = (ix1 & 3) * 1792;
    const int fpy0 = (iy0 & 3) * 448,     fpy1 = (iy1 & 3) * 448;
    const int fpz0 = (iz0 & 3) * 112,     fpz1 = (iz1 & 3) * 112;

    const float4* gp4 = (const float4*)grid;
    const float4* ap4 = (const float4*)atoms;

    float4 c0 = make_float4(0.f,0.f,0.f,0.f), c1 = c0;
    float4 a0 = c0, a1 = c0;
    int pcell = -1;

    #define CORNER(BX,BY,BZ)                                                  \
    {                                                                         \
      const int cp = (BX?cpx1:cpx0) + (BY?cpy1:cpy0) + (BZ?cpz1:cpz0);        \
      const float w = (BX?wx1:wx0) * (BY?wy1:wy0) * (BZ?wz1:wz0);             \
      if (cp != pcell) {                                                      \
        const float4* cv = gp4 + cp;                                          \
        c0 = cv[lane];                                                        \
        if (lane < 48) c1 = cv[64 + lane];                                    \
        pcell = cp;                                                           \
      }                                                                       \
      const float4* fp = ap4 + ((BX?fpx1:fpx0) + (BY?fpy1:fpy0) + (BZ?fpz1:fpz0)); \
      const float4 f0 = fp[lane];                                             \
      a0.x += w*c0.x*f0.x; a0.y += w*c0.y*f0.y;                               \
      a0.z += w*c0.z*f0.z; a0.w += w*c0.w*f0.w;                               \
      if (lane < 48) {                                                        \
        const float4 f1 = fp[64 + lane];                                      \
        a1.x += w*c1.x*f1.x; a1.y += w*c1.y*f1.y;                             \
        a1.z += w*c1.z*f1.z; a1.w += w*c1.w*f1.w;                             \
      }                                                                       \
    }
    // gray order over (x,y,z) bits: consecutive corners differ in one axis
    CORNER(0,0,0) CORNER(0,0,1) CORNER(0,1,1) CORNER(0,1,0)
    CORNER(1,1,0) CORNER(1,1,1) CORNER(1,0,1) CORNER(1,0,0)
    #undef CORNER

    // --- fold to (rgb_pre0..2, sigma) via LDS table, 6-round butterfly ---
    #define DOT4(K,V) ((K).x*(V).x + (K).y*(V).y + (K).z*(V).z + (K).w*(V).w)
    float b0 = DOT4(s_ktab[  0+lane],a0) + DOT4(s_ktab[ 64+lane],a1);
    float b1 = DOT4(s_ktab[128+lane],a0) + DOT4(s_ktab[192+lane],a1);
    float b2 = DOT4(s_ktab[256+lane],a0) + DOT4(s_ktab[320+lane],a1);
    float b3 = DOT4(s_ktab[384+lane],a0) + DOT4(s_ktab[448+lane],a1);
    #undef DOT4
    #pragma unroll
    for (int off = 1; off < 64; off <<= 1) {
      b0 += __shfl_xor(b0, off, 64);
      b1 += __shfl_xor(b1, off, 64);
      b2 += __shfl_xor(b2, off, 64);
      b3 += __shfl_xor(b3, off, 64);
    }

    const float sigma = fmaxf(b3, 0.0f);
    a  = 1.0f - __expf(-sigma * (STEP_F * dnorm));
    r0 = 1.0f/(1.0f + __expf(-b0));
    r1 = 1.0f/(1.0f + __expf(-b1));
    r2 = 1.0f/(1.0f + __expf(-b2));
  }

  if (lane == 0) {
    out[NRAYS*3 + ray*NPT + j] = a;            // alpha output plane (j < 224)
    ws[0*WS_PLANE + ray*WS_RAY_STRIDE + j] = r0;
    ws[1*WS_PLANE + ray*WS_RAY_STRIDE + j] = r1;
    ws[2*WS_PLANE + ray*WS_RAY_STRIDE + j] = r2;
  }
}

// ---------------------------------------------------------------------------
// Kernel B: transmittance scan + reductions. One wave per ray.
// Only j < 256 can have alpha != 0 (memset + JMAX bound) -> 4 chunks.
// ---------------------------------------------------------------------------
__global__ __launch_bounds__(256)
void shdict_scan(const float* __restrict__ rays_o,
                 const float* __restrict__ rays_d,
                 const float* __restrict__ ws,
                 float* __restrict__ out)
{
  const int wave = threadIdx.x >> 6;
  const int lane = threadIdx.x & 63;
  const int ray  = blockIdx.x * 4 + wave;
  if (ray >= NRAYS) return;

  const float ox = rays_o[ray*3+0], oy = rays_o[ray*3+1], oz = rays_o[ray*3+2];
  const float dx = rays_d[ray*3+0], dy = rays_d[ray*3+1], dz = rays_d[ray*3+2];
  const float m0 = fminf((RAD - ox)/dx, (-RAD - ox)/dx);
  const float m1 = fminf((RAD - oy)/dy, (-RAD - oy)/dy);
  const float m2 = fminf((RAD - oz)/dz, (-RAD - oz)/dz);
  const float start = fmaxf(fmaxf(m0, m1), m2);

  const float* alpha = out + NRAYS*3 + ray*NPT;

  float carry = 1.0f;
  float acc = 0.f, dep = 0.f, c0 = 0.f, c1 = 0.f, c2 = 0.f;
  for (int chunk = 0; chunk < 4; ++chunk) {
    const int j = chunk*64 + lane;
    const float a = alpha[j];
    const float v = 1.0f - a + 1e-10f;
    float s = v;
    #pragma unroll
    for (int off = 1; off < 64; off <<= 1) {
      const float o = __shfl_up(s, off, 64);
      if (lane >= off) s *= o;
    }
    float excl = __shfl_up(s, 1, 64);
    if (lane == 0) excl = 1.0f;
    const float T = carry * excl;
    const float al = a * T;
    acc += al;
    const float t = start + (float)j * STEP_F;
    dep += al * t;
    c0 += al * ws[0*WS_PLANE + ray*WS_RAY_STRIDE + j];
    c1 += al * ws[1*WS_PLANE + ray*WS_RAY_STRIDE + j];
    c2 += al * ws[2*WS_PLANE + ray*WS_RAY_STRIDE + j];
    carry *= __shfl(s, 63, 64);
  }
  #pragma unroll
  for (int off = 32; off >= 1; off >>= 1) {
    acc += __shfl_down(acc, off, 64);
    dep += __shfl_down(dep, off, 64);
    c0  += __shfl_down(c0,  off, 64);
    c1  += __shfl_down(c1,  off, 64);
    c2  += __shfl_down(c2,  off, 64);
  }
  if (lane == 0) {
    const float bg = 1.0f - acc;
    out[ray*3+0] = c0 + bg;
    out[ray*3+1] = c1 + bg;
    out[ray*3+2] = c2 + bg;
    out[NRAYS*3 + NRAYS*NPT + ray] = dep;
    if (ray == 0) out[NRAYS*3 + NRAYS*NPT + NRAYS] = 0.0f;
  }
}

// ---------------------------------------------------------------------------
// Fallback: fused single-kernel version (used only if ws is too small).
// ---------------------------------------------------------------------------
__global__ __launch_bounds__(256)
void shdict_render_fused(const float* __restrict__ rays_o,
                         const float* __restrict__ rays_d,
                         const float* __restrict__ grid,
                         const float* __restrict__ atoms,
                         float* __restrict__ out)
{
  const int ray = blockIdx.x;
  const int tid = threadIdx.x;

  __shared__ float s_alpha[NPT];
  __shared__ float s_rgb[NPT][3];

  const float ox = rays_o[ray*3+0], oy = rays_o[ray*3+1], oz = rays_o[ray*3+2];
  const float dx = rays_d[ray*3+0], dy = rays_d[ray*3+1], dz = rays_d[ray*3+2];

  const float m0 = fminf((RAD - ox)/dx, (-RAD - ox)/dx);
  const float m1 = fminf((RAD - oy)/dy, (-RAD - oy)/dy);
  const float m2 = fminf((RAD - oz)/dz, (-RAD - oz)/dz);
  const float start = fmaxf(fmaxf(m0, m1), m2);

  const float dnorm = sqrtf(dx*dx + dy*dy + dz*dz);
  const float inx = dx/dnorm, iny = dy/dnorm, inz = dz/dnorm;
  float sh[9];
  sh[0] = 0.28209479177387814f;
  sh[1] = -0.4886025119029199f*iny;
  sh[2] =  0.4886025119029199f*inz;
  sh[3] = -0.4886025119029199f*inx;
  sh[4] =  1.0925484305920792f*inx*iny;
  sh[5] = -1.0925484305920792f*iny*inz;
  sh[6] =  0.31539156525252005f*(2.0f*inz*inz - inx*inx - iny*iny);
  sh[7] = -1.0925484305920792f*inx*inz;
  sh[8] =  0.5462742152960396f*(inx*inx - iny*iny);

  float* alpha_out = out + NRAYS*3;

  for (int j = tid; j < NPT; j += 256) {
    const float t  = start + (float)j * STEP_F;
    const float px = ox + t*dx;
    const float py = oy + t*dy;
    const float pz = oz + t*dz;
    const bool inb = (px > -RAD) && (px < RAD) && (py > -RAD) && (py < RAD)
                  && (pz > -RAD) && (pz < RAD);
    float a = 0.0f, r0 = 0.5f, r1 = 0.5f, r2 = 0.5f;
    if (inb) {
      const float ux = (px + RAD) / VOXEL_F;
      const float uy = (py + RAD) / VOXEL_F;
      const float uz = (pz + RAD) / VOXEL_F;
      float4 acc4[7];
      #pragma unroll
      for (int q = 0; q < 7; ++q) acc4[q] = make_float4(0.f,0.f,0.f,0.f);
      for (int corner = 0; corner < 8; ++corner) {
        const float sx = (corner & 4) ? 0.5f : -0.5f;
        const float sy = (corner & 2) ? 0.5f : -0.5f;
        const float sz = (corner & 1) ? 0.5f : -0.5f;
        const float pfx = fminf(fmaxf(floorf(ux + sx), 0.0f), 127.0f);
        const float pfy = fminf(fmaxf(floorf(uy + sy), 0.0f), 127.0f);
        const float pfz = fminf(fmaxf(floorf(uz + sz), 0.0f), 127.0f);
        const float fx = fabsf(ux - (pfx + 0.5f));
        const float fy = fabsf(uy - (pfy + 0.5f));
        const float fz = fabsf(uz - (pfz + 0.5f));
        const float w = (1.0f-fx)*(1.0f-fy)*(1.0f-fz);
        const int ix = (int)pfx, iy = (int)pfy, iz = (int)pfz;
        const int cell = ((ix >> 2)*COARSE + (iy >> 2))*COARSE + (iz >> 2);
        const int fine = ((ix & 3)*4 + (iy & 3))*4 + (iz & 3);
        const float4* cv = (const float4*)(grid + (long)cell*448);
        const float4* fv = (const float4*)(atoms + (long)fine*448);
        float4 res[7];
        #pragma unroll
        for (int q = 0; q < 7; ++q) res[q] = make_float4(0.f,0.f,0.f,0.f);
        for (int aa = 0; aa < 16; ++aa) {
          #pragma unroll
          for (int q = 0; q < 7; ++q) {
            const float4 c = cv[aa*7 + q];
            const float4 f = fv[aa*7 + q];
            res[q].x += c.x*f.x;
            res[q].y += c.y*f.y;
            res[q].z += c.z*f.z;
            res[q].w += c.w*f.w;
          }
        }
        #pragma unroll
        for (int q = 0; q < 7; ++q) {
          acc4[q].x += w*res[q].x;
          acc4[q].y += w*res[q].y;
          acc4[q].z += w*res[q].z;
          acc4[q].w += w*res[q].w;
        }
      }
      const float* data = (const float*)acc4;
      const float sigma = fmaxf(data[27], 0.0f);
      a = 1.0f - expf(-sigma * (STEP_F * dnorm));
      float p0 = 0.f, p1 = 0.f, p2 = 0.f;
      #pragma unroll
      for (int k = 0; k < 9; ++k) {
        p0 += sh[k]*data[k];
        p1 += sh[k]*data[9+k];
        p2 += sh[k]*data[18+k];
      }
      r0 = 1.0f/(1.0f + expf(-p0));
      r1 = 1.0f/(1.0f + expf(-p1));
      r2 = 1.0f/(1.0f + expf(-p2));
    }
    s_alpha[j]  = a;
    s_rgb[j][0] = r0; s_rgb[j][1] = r1; s_rgb[j][2] = r2;
    alpha_out[ray*NPT + j] = a;
  }
  __syncthreads();

  if (tid < 64) {
    const int lane = tid;
    float carry = 1.0f;
    float acc = 0.f, dep = 0.f, c0 = 0.f, c1 = 0.f, c2 = 0.f;
    for (int chunk = 0; chunk < 12; ++chunk) {
      const int j = chunk*64 + lane;
      const float a = (j < NPT) ? s_alpha[j] : 0.0f;
      const float v = 1.0f - a + 1e-10f;
      float s = v;
      #pragma unroll
      for (int off = 1; off < 64; off <<= 1) {
        const float o = __shfl_up(s, off, 64);
        if (lane >= off) s *= o;
      }
      float excl = __shfl_up(s, 1, 64);
      if (lane == 0) excl = 1.0f;
      const float T = carry * excl;
      if (j < NPT) {
        const float al = a * T;
        acc += al;
        dep += al * (start + (float)j * STEP_F);
        c0 += al * s_rgb[j][0];
        c1 += al * s_rgb[j][1];
        c2 += al * s_rgb[j][2];
      }
      carry *= __shfl(s, 63, 64);
    }
    #pragma unroll
    for (int off = 32; off >= 1; off >>= 1) {
      acc += __shfl_down(acc, off, 64);
      dep += __shfl_down(dep, off, 64);
      c0  += __shfl_down(c0,  off, 64);
      c1  += __shfl_down(c1,  off, 64);
      c2  += __shfl_down(c2,  off, 64);
    }
    if (lane == 0) {
      const float bg = 1.0f - acc;
      out[ray*3+0] = c0 + bg;
      out[ray*3+1] = c1 + bg;
      out[ray*3+2] = c2 + bg;
      out[NRAYS*3 + NRAYS*NPT + ray] = dep;
      if (ray == 0) out[NRAYS*3 + NRAYS*NPT + NRAYS] = 0.0f;
    }
  }
}

extern "C" void kernel_launch(void* const* d_in, const int* in_sizes, int n_in,
                              void* d_out, int out_size, void* d_ws, size_t ws_size,
                              hipStream_t stream) {
  const float* rays_o = (const float*)d_in[0];
  const float* rays_d = (const float*)d_in[1];
  const float* grid   = (const float*)d_in[2];
  const float* atoms  = (const float*)d_in[3];
  (void)in_sizes; (void)n_in;

  // alpha plane for j >= 224 must be exactly 0 (reference value): zero the
  // whole output first (async memset is graph-capture-safe).
  hipMemsetAsync(d_out, 0, (size_t)out_size * sizeof(float), stream);

  const size_t ws_needed = (size_t)3 * WS_PLANE * sizeof(float);
  if (ws_size >= ws_needed) {
    hipLaunchKernelGGL(shdict_gather, dim3(GATHER_BLOCKS), dim3(256), 0, stream,
                       rays_o, rays_d, grid, atoms, (float*)d_out, (float*)d_ws);
    hipLaunchKernelGGL(shdict_scan, dim3(NRAYS/4), dim3(256), 0, stream,
                       rays_o, rays_d, (const float*)d_ws, (float*)d_out);
  } else {
    hipLaunchKernelGGL(shdict_render_fused, dim3(NRAYS), dim3(256), 0, stream,
                       rays_o, rays_d, grid, atoms, (float*)d_out);
  }
}

// Round 11
// 74.070 us; speedup vs baseline: 6.1230x; 1.4471x over previous
//
#include <hip/hip_runtime.h>
#include <math.h>

namespace {
constexpr int COARSE = 32;
constexpr int NPT    = 767;   // N_INT - 1
constexpr int NRAYS  = 256;
// Max in-cube samples per ray: chord <= 2*R*sqrt(3) = 4.503; STEP = 0.0203125
// -> j < 221.7. JMAX = 224.
constexpr int JMAX   = 224;
constexpr int SEGS   = JMAX / 4;               // 56 (4 waves/block, 1 pt/wave)
constexpr int GATHER_BLOCKS = NRAYS * SEGS;    // 14336 (% 8 == 0)
constexpr int WS_RAY_STRIDE = 256;
constexpr int WS_PLANE = NRAYS * WS_RAY_STRIDE;            // 65536 floats/plane
constexpr int WS_TAB_OFF_F4 = (3 * WS_PLANE) / 4;          // 49152 (float4 idx)
constexpr int WS_RAYDAT_OFF_F = 3 * WS_PLANE + NRAYS*512*4; // 720896 (float idx)
constexpr double VOXEL_D = 1.3 * 2.0 / 32.0 / 4.0;
constexpr float  VOXEL_F  = (float)VOXEL_D;
constexpr float  INV_VOXEL = (float)(1.0 / VOXEL_D);
constexpr float  STEP_F   = (float)(VOXEL_D / 2.0);
constexpr float  RAD      = 1.3f;
}

// ---------------------------------------------------------------------------
// Init: one block per ray. Computes {start, jexit, dist} and the per-ray
// 512-float4 fold table into ws. Runs once; removes the table build + all
// fp32 divides from the 14336-block gather.
// ---------------------------------------------------------------------------
__global__ __launch_bounds__(256)
void shdict_init(const float* __restrict__ rays_o,
                 const float* __restrict__ rays_d,
                 float* __restrict__ ws)
{
  const int ray = blockIdx.x;
  const float ox = rays_o[ray*3+0], oy = rays_o[ray*3+1], oz = rays_o[ray*3+2];
  const float dx = rays_d[ray*3+0], dy = rays_d[ray*3+1], dz = rays_d[ray*3+2];

  const float ax0 = (RAD - ox)/dx, ax1 = (-RAD - ox)/dx;
  const float ay0 = (RAD - oy)/dy, ay1 = (-RAD - oy)/dy;
  const float az0 = (RAD - oz)/dz, az1 = (-RAD - oz)/dz;
  const float start = fmaxf(fmaxf(fminf(ax0,ax1), fminf(ay0,ay1)), fminf(az0,az1));
  const float texit = fminf(fminf(fmaxf(ax0,ax1), fmaxf(ay0,ay1)), fmaxf(az0,az1));
  const float dnorm = sqrtf(dx*dx + dy*dy + dz*dz);
  const float inx = dx/dnorm, iny = dy/dnorm, inz = dz/dnorm;

  if (threadIdx.x == 0) {
    float* rs = ws + WS_RAYDAT_OFF_F + ray*4;
    rs[0] = start;
    rs[1] = (texit - start) / STEP_F;   // jexit
    rs[2] = STEP_F * dnorm;             // dist
    rs[3] = 0.f;
  }

  // fold table: entry [ch*128 + fi] covers elements e = 4*fi .. 4*fi+3
  // (fi < 112; fi >= 112 -> 0). d = e%28; ch 0..2 -> sh[d%9] iff d/9==ch;
  // ch 3 -> (d==27). Same mapping as R10 (verified).
  float4* tab = (float4*)ws + WS_TAB_OFF_F4 + (size_t)ray * 512;
  for (int tix = threadIdx.x; tix < 512; tix += 256) {
    const int ch = tix >> 7;
    const int fi = tix & 127;
    float vv[4];
    #pragma unroll
    for (int comp = 0; comp < 4; ++comp) {
      float val = 0.f;
      if (fi < 112) {
        const int e = 4*fi + comp;
        const int d = e % 28;
        const int dm = d % 9;
        const float shv =
          dm==0 ?  0.28209479177387814f :
          dm==1 ? -0.4886025119029199f*iny :
          dm==2 ?  0.4886025119029199f*inz :
          dm==3 ? -0.4886025119029199f*inx :
          dm==4 ?  1.0925484305920792f*inx*iny :
          dm==5 ? -1.0925484305920792f*iny*inz :
          dm==6 ?  0.31539156525252005f*(2.0f*inz*inz - inx*inx - iny*iny) :
          dm==7 ? -1.0925484305920792f*inx*inz :
                   0.5462742152960396f*(inx*inx - iny*iny);
        if (d == 27) { if (ch == 3) val = 1.0f; }
        else if (d/9 == ch) val = shv;
      }
      vv[comp] = val;
    }
    float4 v; v.x = vv[0]; v.y = vv[1]; v.z = vv[2]; v.w = vv[3];
    tab[tix] = v;
  }
}

// ---------------------------------------------------------------------------
// Gather: one 64-lane wave per sample point, j < 224. No divides, no LDS,
// no table build. wfv-factored corner loop: wf += w*fv per corner (1 fma/elem),
// fold a += cv (.) wf once per coarse-cell group (cells change <= ~3x/point).
// Epilogue fold-table read straight from L2 (per-ray table, 8 KB).
// ---------------------------------------------------------------------------
__global__ __launch_bounds__(256)
void shdict_gather(const float* __restrict__ rays_o,
                   const float* __restrict__ rays_d,
                   const float* __restrict__ grid,
                   const float* __restrict__ atoms,
                   float* __restrict__ out,
                   float* __restrict__ ws)
{
  int bid = blockIdx.x;
  // XCD-chunked bijective swizzle (14336 % 8 == 0)
  bid = (bid & 7) * (GATHER_BLOCKS / 8) + (bid >> 3);

  const int ray  = bid / SEGS;
  const int seg  = bid - ray * SEGS;
  const int lane = threadIdx.x & 63;
  const int wv   = threadIdx.x >> 6;
  const int j    = seg * 4 + wv;          // sample index, < 224

  const float* rs = ws + WS_RAYDAT_OFF_F + ray*4;
  const float start = rs[0];
  const float jexit = rs[1];
  const float dist  = rs[2];

  // whole-block early-out (conservative +2-step margin; NaN-safe)
  if ((float)(seg*4) > jexit + 2.0f) return;

  const float ox = rays_o[ray*3+0], oy = rays_o[ray*3+1], oz = rays_o[ray*3+2];
  const float dx = rays_d[ray*3+0], dy = rays_d[ray*3+1], dz = rays_d[ray*3+2];

  const float t  = start + (float)j * STEP_F;
  const float px = ox + t*dx, py = oy + t*dy, pz = oz + t*dz;
  const bool inb = (px > -RAD) && (px < RAD) && (py > -RAD) && (py < RAD)
                && (pz > -RAD) && (pz < RAD);   // wave-uniform (1 pt/wave)

  float a = 0.f, r0 = 0.5f, r1 = 0.5f, r2 = 0.5f;

  if (inb) {
    const float ux = (px + RAD) * INV_VOXEL;
    const float uy = (py + RAD) * INV_VOXEL;
    const float uz = (pz + RAD) * INV_VOXEL;

    const float pfx0 = fminf(fmaxf(floorf(ux - 0.5f), 0.0f), 127.0f);
    const float pfx1 = fminf(fmaxf(floorf(ux + 0.5f), 0.0f), 127.0f);
    const float pfy0 = fminf(fmaxf(floorf(uy - 0.5f), 0.0f), 127.0f);
    const float pfy1 = fminf(fmaxf(floorf(uy + 0.5f), 0.0f), 127.0f);
    const float pfz0 = fminf(fmaxf(floorf(uz - 0.5f), 0.0f), 127.0f);
    const float pfz1 = fminf(fmaxf(floorf(uz + 0.5f), 0.0f), 127.0f);
    const float wx0 = 1.0f - fabsf(ux - (pfx0 + 0.5f));
    const float wx1 = 1.0f - fabsf(ux - (pfx1 + 0.5f));
    const float wy0 = 1.0f - fabsf(uy - (pfy0 + 0.5f));
    const float wy1 = 1.0f - fabsf(uy - (pfy1 + 0.5f));
    const float wz0 = 1.0f - fabsf(uz - (pfz0 + 0.5f));
    const float wz1 = 1.0f - fabsf(uz - (pfz1 + 0.5f));
    const int ix0 = (int)pfx0, ix1 = (int)pfx1;
    const int iy0 = (int)pfy0, iy1 = (int)pfy1;
    const int iz0 = (int)pfz0, iz1 = (int)pfz1;
    const int cpx0 = (ix0 >> 2) * 114688, cpx1 = (ix1 >> 2) * 114688;
    const int cpy0 = (iy0 >> 2) * 3584,   cpy1 = (iy1 >> 2) * 3584;
    const int cpz0 = (iz0 >> 2) * 112,    cpz1 = (iz1 >> 2) * 112;
    const int fpx0 = (ix0 & 3) * 1792,    fpx1 = (ix1 & 3) * 1792;
    const int fpy0 = (iy0 & 3) * 448,     fpy1 = (iy1 & 3) * 448;
    const int fpz0 = (iz0 & 3) * 112,     fpz1 = (iz1 & 3) * 112;

    const float4* gp4 = (const float4*)grid;
    const float4* ap4 = (const float4*)atoms;

    float4 z4 = make_float4(0.f,0.f,0.f,0.f);
    float4 c0 = z4, c1 = z4;       // current coarse cell data
    float4 wf0 = z4, wf1 = z4;     // w-weighted fv accumulator (current group)
    float4 a0 = z4, a1 = z4;       // folded accumulators
    int pcell = -1;

    #define FOLD() {                                                          \
      a0.x = fmaf(c0.x, wf0.x, a0.x); a0.y = fmaf(c0.y, wf0.y, a0.y);         \
      a0.z = fmaf(c0.z, wf0.z, a0.z); a0.w = fmaf(c0.w, wf0.w, a0.w);         \
      a1.x = fmaf(c1.x, wf1.x, a1.x); a1.y = fmaf(c1.y, wf1.y, a1.y);         \
      a1.z = fmaf(c1.z, wf1.z, a1.z); a1.w = fmaf(c1.w, wf1.w, a1.w);         \
      wf0 = z4; wf1 = z4;                                                     \
    }
    #define CORNER(BX,BY,BZ)                                                  \
    {                                                                         \
      const int cp = (BX?cpx1:cpx0) + (BY?cpy1:cpy0) + (BZ?cpz1:cpz0);        \
      const float w = (BX?wx1:wx0) * (BY?wy1:wy0) * (BZ?wz1:wz0);             \
      if (cp != pcell) {                                                      \
        if (pcell >= 0) FOLD();                                               \
        const float4* cv = gp4 + cp;                                          \
        c0 = cv[lane];                                                        \
        if (lane < 48) c1 = cv[64 + lane];                                    \
        pcell = cp;                                                           \
      }                                                                       \
      const float4* fp = ap4 + ((BX?fpx1:fpx0) + (BY?fpy1:fpy0) + (BZ?fpz1:fpz0)); \
      const float4 f0 = fp[lane];                                             \
      wf0.x = fmaf(w, f0.x, wf0.x); wf0.y = fmaf(w, f0.y, wf0.y);             \
      wf0.z = fmaf(w, f0.z, wf0.z); wf0.w = fmaf(w, f0.w, wf0.w);             \
      if (lane < 48) {                                                        \
        const float4 f1 = fp[64 + lane];                                      \
        wf1.x = fmaf(w, f1.x, wf1.x); wf1.y = fmaf(w, f1.y, wf1.y);           \
        wf1.z = fmaf(w, f1.z, wf1.z); wf1.w = fmaf(w, f1.w, wf1.w);           \
      }                                                                       \
    }
    // gray order over (x,y,z): consecutive corners differ in one axis
    CORNER(0,0,0) CORNER(0,0,1) CORNER(0,1,1) CORNER(0,1,0)
    CORNER(1,1,0) CORNER(1,1,1) CORNER(1,0,1) CORNER(1,0,0)
    FOLD();
    #undef CORNER
    #undef FOLD

    // --- fold to (rgb_pre0..2, sigma) via per-ray table (L2), butterfly ---
    const float4* tab = (const float4*)ws + WS_TAB_OFF_F4 + (size_t)ray * 512;
    #define DOT4(K,V) ((K).x*(V).x + (K).y*(V).y + (K).z*(V).z + (K).w*(V).w)
    float b0 = DOT4(tab[  0+lane],a0) + DOT4(tab[ 64+lane],a1);
    float b1 = DOT4(tab[128+lane],a0) + DOT4(tab[192+lane],a1);
    float b2 = DOT4(tab[256+lane],a0) + DOT4(tab[320+lane],a1);
    float b3 = DOT4(tab[384+lane],a0) + DOT4(tab[448+lane],a1);
    #undef DOT4
    #pragma unroll
    for (int off = 1; off < 64; off <<= 1) {
      b0 += __shfl_xor(b0, off, 64);
      b1 += __shfl_xor(b1, off, 64);
      b2 += __shfl_xor(b2, off, 64);
      b3 += __shfl_xor(b3, off, 64);
    }

    const float sigma = fmaxf(b3, 0.0f);
    a  = 1.0f - __expf(-sigma * dist);
    r0 = __builtin_amdgcn_rcpf(1.0f + __expf(-b0));
    r1 = __builtin_amdgcn_rcpf(1.0f + __expf(-b1));
    r2 = __builtin_amdgcn_rcpf(1.0f + __expf(-b2));
  }

  if (lane == 0) {
    out[NRAYS*3 + ray*NPT + j] = a;            // alpha output plane (j < 224)
    ws[0*WS_PLANE + ray*WS_RAY_STRIDE + j] = r0;
    ws[1*WS_PLANE + ray*WS_RAY_STRIDE + j] = r1;
    ws[2*WS_PLANE + ray*WS_RAY_STRIDE + j] = r2;
  }
}

// ---------------------------------------------------------------------------
// Scan: transmittance + reductions. One wave per ray; only j < 256 nonzero.
// ---------------------------------------------------------------------------
__global__ __launch_bounds__(256)
void shdict_scan(const float* __restrict__ rays_o,
                 const float* __restrict__ rays_d,
                 const float* __restrict__ ws,
                 float* __restrict__ out)
{
  const int wave = threadIdx.x >> 6;
  const int lane = threadIdx.x & 63;
  const int ray  = blockIdx.x * 4 + wave;
  if (ray >= NRAYS) return;

  const float ox = rays_o[ray*3+0], oy = rays_o[ray*3+1], oz = rays_o[ray*3+2];
  const float dx = rays_d[ray*3+0], dy = rays_d[ray*3+1], dz = rays_d[ray*3+2];
  const float m0 = fminf((RAD - ox)/dx, (-RAD - ox)/dx);
  const float m1 = fminf((RAD - oy)/dy, (-RAD - oy)/dy);
  const float m2 = fminf((RAD - oz)/dz, (-RAD - oz)/dz);
  const float start = fmaxf(fmaxf(m0, m1), m2);

  const float* alpha = out + NRAYS*3 + ray*NPT;

  float carry = 1.0f;
  float acc = 0.f, dep = 0.f, c0 = 0.f, c1 = 0.f, c2 = 0.f;
  for (int chunk = 0; chunk < 4; ++chunk) {
    const int j = chunk*64 + lane;
    const float a = alpha[j];
    const float v = 1.0f - a + 1e-10f;
    float s = v;
    #pragma unroll
    for (int off = 1; off < 64; off <<= 1) {
      const float o = __shfl_up(s, off, 64);
      if (lane >= off) s *= o;
    }
    float excl = __shfl_up(s, 1, 64);
    if (lane == 0) excl = 1.0f;
    const float T = carry * excl;
    const float al = a * T;
    acc += al;
    const float t = start + (float)j * STEP_F;
    dep += al * t;
    c0 += al * ws[0*WS_PLANE + ray*WS_RAY_STRIDE + j];
    c1 += al * ws[1*WS_PLANE + ray*WS_RAY_STRIDE + j];
    c2 += al * ws[2*WS_PLANE + ray*WS_RAY_STRIDE + j];
    carry *= __shfl(s, 63, 64);
  }
  #pragma unroll
  for (int off = 32; off >= 1; off >>= 1) {
    acc += __shfl_down(acc, off, 64);
    dep += __shfl_down(dep, off, 64);
    c0  += __shfl_down(c0,  off, 64);
    c1  += __shfl_down(c1,  off, 64);
    c2  += __shfl_down(c2,  off, 64);
  }
  if (lane == 0) {
    const float bg = 1.0f - acc;
    out[ray*3+0] = c0 + bg;
    out[ray*3+1] = c1 + bg;
    out[ray*3+2] = c2 + bg;
    out[NRAYS*3 + NRAYS*NPT + ray] = dep;
    if (ray == 0) out[NRAYS*3 + NRAYS*NPT + NRAYS] = 0.0f;
  }
}

// ---------------------------------------------------------------------------
// Fallback: fused single-kernel version (used only if ws is too small).
// ---------------------------------------------------------------------------
__global__ __launch_bounds__(256)
void shdict_render_fused(const float* __restrict__ rays_o,
                         const float* __restrict__ rays_d,
                         const float* __restrict__ grid,
                         const float* __restrict__ atoms,
                         float* __restrict__ out)
{
  const int ray = blockIdx.x;
  const int tid = threadIdx.x;

  __shared__ float s_alpha[NPT];
  __shared__ float s_rgb[NPT][3];

  const float ox = rays_o[ray*3+0], oy = rays_o[ray*3+1], oz = rays_o[ray*3+2];
  const float dx = rays_d[ray*3+0], dy = rays_d[ray*3+1], dz = rays_d[ray*3+2];

  const float m0 = fminf((RAD - ox)/dx, (-RAD - ox)/dx);
  const float m1 = fminf((RAD - oy)/dy, (-RAD - oy)/dy);
  const float m2 = fminf((RAD - oz)/dz, (-RAD - oz)/dz);
  const float start = fmaxf(fmaxf(m0, m1), m2);

  const float dnorm = sqrtf(dx*dx + dy*dy + dz*dz);
  const float inx = dx/dnorm, iny = dy/dnorm, inz = dz/dnorm;
  float sh[9];
  sh[0] = 0.28209479177387814f;
  sh[1] = -0.4886025119029199f*iny;
  sh[2] =  0.4886025119029199f*inz;
  sh[3] = -0.4886025119029199f*inx;
  sh[4] =  1.0925484305920792f*inx*iny;
  sh[5] = -1.0925484305920792f*iny*inz;
  sh[6] =  0.31539156525252005f*(2.0f*inz*inz - inx*inx - iny*iny);
  sh[7] = -1.0925484305920792f*inx*inz;
  sh[8] =  0.5462742152960396f*(inx*inx - iny*iny);

  float* alpha_out = out + NRAYS*3;

  for (int j = tid; j < NPT; j += 256) {
    const float t  = start + (float)j * STEP_F;
    const float px = ox + t*dx;
    const float py = oy + t*dy;
    const float pz = oz + t*dz;
    const bool inb = (px > -RAD) && (px < RAD) && (py > -RAD) && (py < RAD)
                  && (pz > -RAD) && (pz < RAD);
    float a = 0.0f, r0 = 0.5f, r1 = 0.5f, r2 = 0.5f;
    if (inb) {
      const float ux = (px + RAD) / VOXEL_F;
      const float uy = (py + RAD) / VOXEL_F;
      const float uz = (pz + RAD) / VOXEL_F;
      float4 acc4[7];
      #pragma unroll
      for (int q = 0; q < 7; ++q) acc4[q] = make_float4(0.f,0.f,0.f,0.f);
      for (int corner = 0; corner < 8; ++corner) {
        const float sx = (corner & 4) ? 0.5f : -0.5f;
        const float sy = (corner & 2) ? 0.5f : -0.5f;
        const float sz = (corner & 1) ? 0.5f : -0.5f;
        const float pfx = fminf(fmaxf(floorf(ux + sx), 0.0f), 127.0f);
        const float pfy = fminf(fmaxf(floorf(uy + sy), 0.0f), 127.0f);
        const float pfz = fminf(fmaxf(floorf(uz + sz), 0.0f), 127.0f);
        const float fx = fabsf(ux - (pfx + 0.5f));
        const float fy = fabsf(uy - (pfy + 0.5f));
        const float fz = fabsf(uz - (pfz + 0.5f));
        const float w = (1.0f-fx)*(1.0f-fy)*(1.0f-fz);
        const int ix = (int)pfx, iy = (int)pfy, iz = (int)pfz;
        const int cell = ((ix >> 2)*COARSE + (iy >> 2))*COARSE + (iz >> 2);
        const int fine = ((ix & 3)*4 + (iy & 3))*4 + (iz & 3);
        const float4* cv = (const float4*)(grid + (long)cell*448);
        const float4* fv = (const float4*)(atoms + (long)fine*448);
        float4 res[7];
        #pragma unroll
        for (int q = 0; q < 7; ++q) res[q] = make_float4(0.f,0.f,0.f,0.f);
        for (int aa = 0; aa < 16; ++aa) {
          #pragma unroll
          for (int q = 0; q < 7; ++q) {
            const float4 c = cv[aa*7 + q];
            const float4 f = fv[aa*7 + q];
            res[q].x += c.x*f.x;
            res[q].y += c.y*f.y;
            res[q].z += c.z*f.z;
            res[q].w += c.w*f.w;
          }
        }
        #pragma unroll
        for (int q = 0; q < 7; ++q) {
          acc4[q].x += w*res[q].x;
          acc4[q].y += w*res[q].y;
          acc4[q].z += w*res[q].z;
          acc4[q].w += w*res[q].w;
        }
      }
      const float* data = (const float*)acc4;
      const float sigma = fmaxf(data[27], 0.0f);
      a = 1.0f - expf(-sigma * (STEP_F * dnorm));
      float p0 = 0.f, p1 = 0.f, p2 = 0.f;
      #pragma unroll
      for (int k = 0; k < 9; ++k) {
        p0 += sh[k]*data[k];
        p1 += sh[k]*data[9+k];
        p2 += sh[k]*data[18+k];
      }
      r0 = 1.0f/(1.0f + expf(-p0));
      r1 = 1.0f/(1.0f + expf(-p1));
      r2 = 1.0f/(1.0f + expf(-p2));
    }
    s_alpha[j]  = a;
    s_rgb[j][0] = r0; s_rgb[j][1] = r1; s_rgb[j][2] = r2;
    alpha_out[ray*NPT + j] = a;
  }
  __syncthreads();

  if (tid < 64) {
    const int lane = tid;
    float carry = 1.0f;
    float acc = 0.f, dep = 0.f, c0 = 0.f, c1 = 0.f, c2 = 0.f;
    for (int chunk = 0; chunk < 12; ++chunk) {
      const int j = chunk*64 + lane;
      const float a = (j < NPT) ? s_alpha[j] : 0.0f;
      const float v = 1.0f - a + 1e-10f;
      float s = v;
      #pragma unroll
      for (int off = 1; off < 64; off <<= 1) {
        const float o = __shfl_up(s, off, 64);
        if (lane >= off) s *= o;
      }
      float excl = __shfl_up(s, 1, 64);
      if (lane == 0) excl = 1.0f;
      const float T = carry * excl;
      if (j < NPT) {
        const float al = a * T;
        acc += al;
        dep += al * (start + (float)j * STEP_F);
        c0 += al * s_rgb[j][0];
        c1 += al * s_rgb[j][1];
        c2 += al * s_rgb[j][2];
      }
      carry *= __shfl(s, 63, 64);
    }
    #pragma unroll
    for (int off = 32; off >= 1; off >>= 1) {
      acc += __shfl_down(acc, off, 64);
      dep += __shfl_down(dep, off, 64);
      c0  += __shfl_down(c0,  off, 64);
      c1  += __shfl_down(c1,  off, 64);
      c2  += __shfl_down(c2,  off, 64);
    }
    if (lane == 0) {
      const float bg = 1.0f - acc;
      out[ray*3+0] = c0 + bg;
      out[ray*3+1] = c1 + bg;
      out[ray*3+2] = c2 + bg;
      out[NRAYS*3 + NRAYS*NPT + ray] = dep;
      if (ray == 0) out[NRAYS*3 + NRAYS*NPT + NRAYS] = 0.0f;
    }
  }
}

extern "C" void kernel_launch(void* const* d_in, const int* in_sizes, int n_in,
                              void* d_out, int out_size, void* d_ws, size_t ws_size,
                              hipStream_t stream) {
  const float* rays_o = (const float*)d_in[0];
  const float* rays_d = (const float*)d_in[1];
  const float* grid   = (const float*)d_in[2];
  const float* atoms  = (const float*)d_in[3];
  (void)in_sizes; (void)n_in;

  // alpha plane for j >= 224 must be exactly 0 (the reference value there)
  hipMemsetAsync(d_out, 0, (size_t)out_size * sizeof(float), stream);

  const size_t ws_needed = (size_t)(WS_RAYDAT_OFF_F + NRAYS*4) * sizeof(float);
  if (ws_size >= ws_needed) {
    hipLaunchKernelGGL(shdict_init, dim3(NRAYS), dim3(256), 0, stream,
                       rays_o, rays_d, (float*)d_ws);
    hipLaunchKernelGGL(shdict_gather, dim3(GATHER_BLOCKS), dim3(256), 0, stream,
                       rays_o, rays_d, grid, atoms, (float*)d_out, (float*)d_ws);
    hipLaunchKernelGGL(shdict_scan, dim3(NRAYS/4), dim3(256), 0, stream,
                       rays_o, rays_d, (const float*)d_ws, (float*)d_out);
  } else {
    hipLaunchKernelGGL(shdict_render_fused, dim3(NRAYS), dim3(256), 0, stream,
                       rays_o, rays_d, grid, atoms, (float*)d_out);
  }
}